// Round 1
// baseline (824.111 us; speedup 1.0000x reference)
//
#include <hip/hip_runtime.h>

#define B_ 128
#define L_ 64
#define V_ 8192
#define E_ 128
#define H_ 128
#define NROW (B_*L_)
#define HSTRIDE 136
#define AS 136
#define XS 264
#define YS 136
#define ZS 132

typedef unsigned short u16;
typedef __attribute__((ext_vector_type(8))) short bf16x8;
typedef __attribute__((ext_vector_type(4))) float f32x4;

__device__ __forceinline__ float sigm(float x){ return 1.f/(1.f + __expf(-x)); }
__device__ __forceinline__ float ftanh(float x){ float e = __expf(2.f*x); return 1.f - 2.f/(e + 1.f); }
__device__ __forceinline__ u16 f2bf(float f){
    union { unsigned int i; float f; } x; x.f = f;
    unsigned int r = x.i + 0x7fff + ((x.i >> 16) & 1);
    return (u16)(r >> 16);
}
// raw barrier: LDS-only sync, no vmcnt drain (global loads/stores stay in flight)
#define LBAR() asm volatile("s_waitcnt lgkmcnt(0)\ns_barrier" ::: "memory")

__device__ __forceinline__ bf16x8 pack8(const float* p){
    const float4* q = (const float4*)p;
    float4 a = q[0], b = q[1];
    bf16x8 f;
    f[0]=(short)f2bf(a.x); f[1]=(short)f2bf(a.y); f[2]=(short)f2bf(a.z); f[3]=(short)f2bf(a.w);
    f[4]=(short)f2bf(b.x); f[5]=(short)f2bf(b.y); f[6]=(short)f2bf(b.z); f[7]=(short)f2bf(b.w);
    return f;
}

// ---------------------------------------------------------------- transpose W_visit [E,V] -> WT [V,E]
__global__ __launch_bounds__(256) void k_transpose_wv(const float* __restrict__ Wv, float* __restrict__ WT){
    __shared__ float tile[16][129];
    int v0 = blockIdx.x * 16;
    int t = threadIdx.x;
    #pragma unroll
    for(int i=0;i<8;i++){
        int idx = i*256 + t; int e = idx >> 4; int vv = idx & 15;
        tile[vv][e] = Wv[(size_t)e*V_ + v0 + vv];
    }
    __syncthreads();
    #pragma unroll
    for(int i=0;i<8;i++){
        int idx = i*256 + t; int vv = idx >> 7; int e = idx & 127;
        WT[(size_t)(v0+vv)*E_ + e] = tile[vv][e];
    }
}

// ---------------------------------------------------------------- v = (x @ Wv^T + bin_embed[delta]) * m
__global__ __launch_bounds__(256) void k_visit_embed(const float* __restrict__ px, const float* __restrict__ vmask,
                                                     const int* __restrict__ bins, const float* __restrict__ bemb,
                                                     const float* __restrict__ WT, float* __restrict__ v){
    __shared__ int idxs[512];
    __shared__ int cnt;
    __shared__ int dsh;
    __shared__ float msh;
    __shared__ float4 red[8][32];
    int row = blockIdx.x; int l = row & 63;
    int t = threadIdx.x;
    if(t==0){
        cnt = 0;
        float m = vmask[row];
        int d = 0;
        if(l > 0){ d = bins[row] - bins[row-1]; d = d < 0 ? 0 : (d > 513 ? 513 : d); }
        if(!(m > 0.f)) d = 0;
        dsh = d; msh = m;
    }
    __syncthreads();
    const uint4* xr4 = (const uint4*)(px + (size_t)row * V_);
    for(int i=t;i<2048;i+=256){
        uint4 u = xr4[i];
        unsigned int w[4] = {u.x,u.y,u.z,u.w};
        #pragma unroll
        for(int j=0;j<4;j++){
            if(w[j]){ int p = atomicAdd(&cnt,1); if(p<512) idxs[p] = i*4 + j; }
        }
    }
    __syncthreads();
    int n = cnt; if(n > 512) n = 512;
    int eq = t & 31, jg = t >> 5;
    float4 a4 = {0.f,0.f,0.f,0.f};
    for(int j=jg;j<n;j+=8){
        const float4* wr = (const float4*)(WT + (size_t)idxs[j]*E_);
        float4 wv = wr[eq];
        a4.x += wv.x; a4.y += wv.y; a4.z += wv.z; a4.w += wv.w;
    }
    red[jg][eq] = a4;
    __syncthreads();
    if(t < 32){
        float4 s = red[0][t];
        #pragma unroll
        for(int g=1;g<8;g++){
            float4 r = red[g][t];
            s.x += r.x; s.y += r.y; s.z += r.z; s.w += r.w;
        }
        const float4* bp = (const float4*)(bemb + dsh*E_);
        float4 bv = bp[t];
        float m = msh;
        float4 o;
        o.x = (s.x + bv.x)*m; o.y = (s.y + bv.y)*m; o.z = (s.z + bv.z)*m; o.w = (s.w + bv.w)*m;
        ((float4*)(v + (size_t)row*E_))[t] = o;
    }
}

// ---------------------------------------------------------------- LSTM fused: on-the-fly input GEMM + recurrence + hp + logits
template<bool DOHP>
__device__ __forceinline__ void lstm_step(int l,
        const u16* __restrict__ bufr, u16* __restrict__ bufw,
        const u16* __restrict__ vbr, u16* __restrict__ vbw,
        const float*& pv, float*& hpb,
        const bf16x8 (&bfh)[4][4], const bf16x8 (&bfv)[4][4], const bf16x8 (&wp)[4],
        const float (&bb)[4], float (&c4)[4], float (&lg4)[4], const int (&len4)[4],
        float wcv, int t, int lc, int quad, int cw){
    // issue v-prefetch for step l+1 first (longest latency; L2/L3-resident)
    float4 vnx;
    if(l+1 < 64){ vnx = *(const float4*)pv; pv += E_; }
    bf16x8 afh[4], afv[4];
    #pragma unroll
    for(int kt=0;kt<4;kt++){
        afh[kt] = *(const bf16x8*)&bufr[lc*HSTRIDE + kt*32 + quad*8];
        afv[kt] = *(const bf16x8*)&vbr[lc*AS + kt*32 + quad*8];
    }
    f32x4 acc[4], acch;
    #pragma unroll
    for(int g=0;g<4;g++) acc[g] = (f32x4){0.f,0.f,0.f,0.f};
    acch = (f32x4){0.f,0.f,0.f,0.f};
    #pragma unroll
    for(int kt=0;kt<4;kt++){
        #pragma unroll
        for(int g=0;g<4;g++){
            acc[g] = __builtin_amdgcn_mfma_f32_16x16x32_bf16(afh[kt], bfh[g][kt], acc[g], 0,0,0);
            acc[g] = __builtin_amdgcn_mfma_f32_16x16x32_bf16(afv[kt], bfv[g][kt], acc[g], 0,0,0);
        }
        if constexpr (DOHP)
            acch = __builtin_amdgcn_mfma_f32_16x16x32_bf16(afh[kt], wp[kt], acch, 0,0,0);
    }
    if constexpr (DOHP){
        // hp[b,l] = h_{l-1} @ Wproj^T  (af IS h_{l-1}; h=0 at l=0 -> hp=0).
        // Mask multiply dropped: masked-row hp never reaches a checked output
        // (loss re-masks with mrow, z-updates re-mask with m, logits index < len).
        #pragma unroll
        for(int r=0;r<4;r++) hpb[(size_t)r*64*E_] = acch[r];
        hpb += E_;
    }
    #pragma unroll
    for(int r=0;r<4;r++){
        float gi = acc[0][r] + bb[0];
        float gf = acc[1][r] + bb[1];
        float gg = acc[2][r] + bb[2];
        float go = acc[3][r] + bb[3];
        float c  = sigm(gf)*c4[r] + sigm(gi)*ftanh(gg);
        float h  = sigm(go)*ftanh(c);
        c4[r] = c;
        bufw[(quad*4+r)*HSTRIDE + cw] = f2bf(h);
        if(l == len4[r]-1) lg4[r] += h * wcv;
    }
    // stage prefetched v row-block for l+1 into the other LDS buffer
    if(l+1 < 64){
        int sr = t >> 5, se = (t & 31)*4;
        u16* d = vbw + sr*AS + se;
        d[0]=f2bf(vnx.x); d[1]=f2bf(vnx.y); d[2]=f2bf(vnx.z); d[3]=f2bf(vnx.w);
    }
    LBAR();
}

template<bool DOHP>
__global__ __launch_bounds__(512,2) void k_lstm_fused(const float* __restrict__ vin,
        const float* __restrict__ Whh, const float* __restrict__ Wih,
        const float* __restrict__ bih, const float* __restrict__ bhh,
        const float* __restrict__ Wproj, const float* __restrict__ Wcls, const float* __restrict__ bcls,
        const float* __restrict__ vmask, float* __restrict__ hp_out, float* __restrict__ logits_out){
    __shared__ __align__(16) u16 hbuf[2][16*HSTRIDE];
    __shared__ __align__(16) u16 vbuf[2][16*AS];
    __shared__ float vmsh[16*64];
    __shared__ int lensh[16];
    __shared__ float lgsh[16][132];
    int t = threadIdx.x;
    int wave = t >> 6, lane = t & 63;
    int quad = lane >> 4, lc = lane & 15;
    int cw = wave*16 + lc;
    int b0 = blockIdx.x * 16;

    for(int i=t;i<16*HSTRIDE;i+=512) hbuf[0][i] = 0;
    for(int i=t;i<1024;i+=512) vmsh[i] = vmask[b0*64 + i];
    // stage v for l=0; pv then points at this thread's l=1 element
    const float* pv = vin + (size_t)(b0 + (t>>5))*64*E_ + (t&31)*4;
    {
        float4 v0 = *(const float4*)pv; pv += E_;
        u16* d = &vbuf[0][(t>>5)*AS + (t&31)*4];
        d[0]=f2bf(v0.x); d[1]=f2bf(v0.y); d[2]=f2bf(v0.z); d[3]=f2bf(v0.w);
    }
    __syncthreads();
    if(t < 16){
        int s = 0;
        #pragma unroll
        for(int i=0;i<64;i++) s += (vmsh[t*64 + i] > 0.f) ? 1 : 0;
        lensh[t] = s < 1 ? 1 : s;
    }

    bf16x8 bfh[4][4], bfv[4][4], wp[4];
    float bb[4];
    #pragma unroll
    for(int g=0;g<4;g++){
        int n = g*128 + cw;
        bb[g] = bih[n] + bhh[n];
        const float* wrh = Whh + (size_t)n*H_ + quad*8;
        const float* wrv = Wih + (size_t)n*E_ + quad*8;
        #pragma unroll
        for(int kt=0;kt<4;kt++){ bfh[g][kt] = pack8(wrh + kt*32); bfv[g][kt] = pack8(wrv + kt*32); }
    }
    if constexpr (DOHP){
        const float* wr = Wproj + (size_t)cw*H_ + quad*8;
        #pragma unroll
        for(int kt=0;kt<4;kt++) wp[kt] = pack8(wr + kt*32);
    }
    float wcv = Wcls[cw];
    float c4[4] = {0.f,0.f,0.f,0.f};
    float lg4[4] = {0.f,0.f,0.f,0.f};
    float* hpb = DOHP ? (hp_out + (size_t)(b0 + quad*4)*64*E_ + cw) : nullptr;
    __syncthreads();
    int len4[4];
    #pragma unroll
    for(int r=0;r<4;r++) len4[r] = lensh[quad*4 + r];

    for(int lb=0;lb<64;lb+=2){
        lstm_step<DOHP>(lb,   hbuf[0], hbuf[1], vbuf[0], vbuf[1], pv, hpb, bfh, bfv, wp, bb, c4, lg4, len4, wcv, t, lc, quad, cw);
        lstm_step<DOHP>(lb+1, hbuf[1], hbuf[0], vbuf[1], vbuf[0], pv, hpb, bfh, bfv, wp, bb, c4, lg4, len4, wcv, t, lc, quad, cw);
    }
    #pragma unroll
    for(int r=0;r<4;r++) lgsh[quad*4+r][cw] = lg4[r];
    __syncthreads();
    {
        int row = t >> 5, l32 = t & 31;
        float s = lgsh[row][l32] + lgsh[row][l32+32] + lgsh[row][l32+64] + lgsh[row][l32+96];
        s += __shfl_down(s, 16, 32);
        s += __shfl_down(s, 8, 32);
        s += __shfl_down(s, 4, 32);
        s += __shfl_down(s, 2, 32);
        s += __shfl_down(s, 1, 32);
        if(l32 == 0) logits_out[b0 + row] = s + bcls[0];
    }
}

// ---------------------------------------------------------------- fused: diff_loss + reverse diffusion -> v_syn
__global__ __launch_bounds__(256,2) void k_drg(const float* __restrict__ v, const float* __restrict__ hp,
        const float* __restrict__ eps, const int* __restrict__ tdiff, const float* __restrict__ vmask,
        const float* __restrict__ z0, const float* __restrict__ noise, const float* __restrict__ temb,
        const float* __restrict__ Wf, const float* __restrict__ bfu,
        const float* __restrict__ We1, const float* __restrict__ be1,
        const float* __restrict__ We2, const float* __restrict__ be2,
        float* __restrict__ partial, float* __restrict__ vsyn){
    __shared__ __align__(16) float zbuf[16*ZS];
    __shared__ float hpbuf[16*ZS];
    __shared__ __align__(16) u16 xbuf[16*XS];
    __shared__ __align__(16) u16 y1buf[16*YS];
    __shared__ float wfsh[512];
    __shared__ float ssh[16][2], hpd[16][2];
    __shared__ float mrow[16]; __shared__ int trow[16];
    __shared__ float sbeta[10], sabar[10];
    __shared__ float rb[4];
    int row0 = blockIdx.x * 16; int t = threadIdx.x;
    int wave = t >> 6, lane = t & 63, quad = lane >> 4, lc = lane & 15;

    if(t==0){
        float p = 1.f;
        for(int k=0;k<10;k++){ float b = 1e-4f + (0.02f - 1e-4f)*k/9.f; sbeta[k] = b; p *= (1.f - b); sabar[k] = p; }
    }
    if(t < 16){
        int row = row0 + t; float m = vmask[row];
        mrow[t] = m; trow[t] = (m > 0.f) ? tdiff[row >> 6] : 1;
    }
    for(int i=t;i<512;i+=256) wfsh[i] = Wf[i];
    __syncthreads();
    // z_t (diffusion-loss forward sample) and hp into LDS
    #pragma unroll
    for(int i=0;i<8;i++){
        int flat = i*256 + t; int r = flat >> 7; int e = flat & 127; int row = row0 + r;
        float ab = sabar[trow[r]-1];
        zbuf[r*ZS + e] = (sqrtf(ab)*v[(size_t)row*E_ + e] + sqrtf(1.f - ab)*eps[(size_t)row*E_ + e]) * mrow[r];
        hpbuf[r*ZS + e] = hp[(size_t)row*E_ + e];
    }
    bf16x8 wf1[2][8], wf2[2][4];
    float be1v[2], be2v[2];
    #pragma unroll
    for(int nt=0;nt<2;nt++){
        int n = wave*32 + nt*16 + lc;
        be1v[nt] = be1[n]; be2v[nt] = be2[n];
        const float* w1 = We1 + (size_t)n*256 + quad*8;
        #pragma unroll
        for(int kt=0;kt<8;kt++) wf1[nt][kt] = pack8(w1 + kt*32);
        const float* w2 = We2 + (size_t)n*128 + quad*8;
        #pragma unroll
        for(int kt=0;kt<4;kt++) wf2[nt][kt] = pack8(w2 + kt*32);
    }
    __syncthreads();
    // hp·Wf[:,128:256]+bfu (reused by both diff and all 10 reverse steps)
    {
        int row = t >> 4, k = (t >> 3) & 1, sub = t & 7;
        float p = 0.f;
        #pragma unroll
        for(int i=0;i<16;i++)
            p += hpbuf[row*ZS + sub*16 + i] * wfsh[k*256 + 128 + sub*16 + i];
        p += __shfl_down(p,4); p += __shfl_down(p,2); p += __shfl_down(p,1);
        if(sub == 0) hpd[row][k] = p + bfu[k];
    }
    __syncthreads();

    // ---------- 11 fuse_eps evaluations: s=0 -> diff loss on z_t; s=1..10 -> reverse steps
    for(int s=0;s<11;s++){
        int kk = 11 - s;                // reverse step index for s>=1
        // prefetch this iteration's global inputs early (hidden under dot+MFMA phases)
        float nzv[8], epv[8], z0v[8];
        if(s >= 1){
            #pragma unroll
            for(int nt=0;nt<2;nt++)
                #pragma unroll
                for(int r=0;r<4;r++)
                    nzv[nt*4+r] = noise[((size_t)(s-1)*NROW + row0 + quad*4 + r)*E_ + wave*32 + nt*16 + lc];
        } else {
            #pragma unroll
            for(int nt=0;nt<2;nt++)
                #pragma unroll
                for(int r=0;r<4;r++)
                    epv[nt*4+r] = eps[(size_t)(row0 + quad*4 + r)*E_ + wave*32 + nt*16 + lc];
            #pragma unroll
            for(int i=0;i<8;i++){
                int flat = i*256 + t;
                z0v[i] = z0[(size_t)(row0 + (flat >> 7))*E_ + (flat & 127)];
            }
        }
        {
            int row = t >> 4, k = (t >> 3) & 1, sub = t & 7;
            float q = 0.f;
            #pragma unroll
            for(int i=0;i<16;i++)
                q += zbuf[row*ZS + sub*16 + i] * wfsh[k*256 + sub*16 + i];
            q += __shfl_down(q,4); q += __shfl_down(q,2); q += __shfl_down(q,1);
            if(sub == 0) ssh[row][k] = q + hpd[row][k];
        }
        __syncthreads();
        {
            int row = t >> 4, c0 = (t & 15) * 16;
            float s0 = ssh[row][0], s1 = ssh[row][1];
            float a0 = 1.f/(1.f + __expf(s1 - s0)), a1 = 1.f - a0;
            int tt = (s == 0) ? trow[row] : ((mrow[row] > 0.f) ? kk : 1);
            #pragma unroll
            for(int i=0;i<16;i++){
                int c = c0 + i;
                float val = (c < 128) ? (a0*zbuf[row*ZS + c] + a1*hpbuf[row*ZS + c])
                                      : temb[tt*E_ + (c - 128)];
                xbuf[row*XS + c] = f2bf(val);
            }
        }
        __syncthreads();
        f32x4 acc1[2];
        acc1[0] = (f32x4){0.f,0.f,0.f,0.f}; acc1[1] = (f32x4){0.f,0.f,0.f,0.f};
        #pragma unroll
        for(int kt=0;kt<8;kt++){
            bf16x8 af = *(const bf16x8*)&xbuf[lc*XS + kt*32 + quad*8];
            acc1[0] = __builtin_amdgcn_mfma_f32_16x16x32_bf16(af, wf1[0][kt], acc1[0], 0,0,0);
            acc1[1] = __builtin_amdgcn_mfma_f32_16x16x32_bf16(af, wf1[1][kt], acc1[1], 0,0,0);
        }
        #pragma unroll
        for(int nt=0;nt<2;nt++){
            #pragma unroll
            for(int r=0;r<4;r++)
                y1buf[(quad*4+r)*YS + wave*32 + nt*16 + lc] = f2bf(fmaxf(acc1[nt][r] + be1v[nt], 0.f));
        }
        __syncthreads();
        f32x4 acc2[2];
        acc2[0] = (f32x4){0.f,0.f,0.f,0.f}; acc2[1] = (f32x4){0.f,0.f,0.f,0.f};
        #pragma unroll
        for(int kt=0;kt<4;kt++){
            bf16x8 af = *(const bf16x8*)&y1buf[lc*YS + kt*32 + quad*8];
            acc2[0] = __builtin_amdgcn_mfma_f32_16x16x32_bf16(af, wf2[0][kt], acc2[0], 0,0,0);
            acc2[1] = __builtin_amdgcn_mfma_f32_16x16x32_bf16(af, wf2[1][kt], acc2[1], 0,0,0);
        }
        if(s == 0){
            // diffusion loss partial; then load z0 (prefetched) for the reverse chain
            float lp = 0.f;
            #pragma unroll
            for(int nt=0;nt<2;nt++){
                #pragma unroll
                for(int r=0;r<4;r++){
                    int m = quad*4 + r;
                    float d = (acc2[nt][r] + be2v[nt]) - epv[nt*4+r];
                    lp += d*d*mrow[m];
                }
            }
            #pragma unroll
            for(int off=32;off;off>>=1) lp += __shfl_down(lp, off);
            if(lane == 0) rb[wave] = lp;
            __syncthreads();
            if(t == 0) partial[blockIdx.x] = rb[0]+rb[1]+rb[2]+rb[3];
            #pragma unroll
            for(int i=0;i<8;i++){
                int flat = i*256 + t; int r = flat >> 7; int e = flat & 127;
                zbuf[r*ZS + e] = z0v[i];
            }
            __syncthreads();
        } else {
            float beta = sbeta[kk-1];
            float c1 = beta / sqrtf(1.f - sabar[kk-1]);
            float c2 = 1.f / sqrtf(1.f - beta);
            float sb = sqrtf(beta);
            #pragma unroll
            for(int nt=0;nt<2;nt++){
                int n = wave*32 + nt*16 + lc;
                #pragma unroll
                for(int r=0;r<4;r++){
                    int m = quad*4 + r;
                    float e = acc2[nt][r] + be2v[nt];
                    float z = zbuf[m*ZS + n];
                    float mean = (z - c1*e) * c2;
                    float nz = nzv[nt*4+r];
                    float znew = (kk > 1) ? (mean + sb*nz) : mean;
                    zbuf[m*ZS + n] = znew * mrow[m];
                }
            }
            __syncthreads();
        }
    }
    // ---------- write v_syn (final zbuf) as f32; lstm2 computes its input GEMM on the fly
    {
        int r = t >> 4, e0 = (t & 15) * 8;
        float4 a = *(const float4*)&zbuf[r*ZS + e0];
        float4 b2 = *(const float4*)&zbuf[r*ZS + e0 + 4];
        *(float4*)&vsyn[(size_t)(row0 + r)*E_ + e0] = a;
        *(float4*)&vsyn[(size_t)(row0 + r)*E_ + e0 + 4] = b2;
    }
}

// ---------------------------------------------------------------- loss finalize (sums 512 partials + mask)
__global__ void k_finalize(const float* __restrict__ partial, const float* __restrict__ vmask, float* __restrict__ out){
    __shared__ float rb[4], rl[4];
    int t = threadIdx.x;
    float s = 0.f;
    for(int i=t;i<NROW;i+=256) s += vmask[i];
    float ls = 0.f;
    for(int i=t;i<512;i+=256) ls += partial[i];
    #pragma unroll
    for(int off=32;off;off>>=1){ s += __shfl_down(s, off); ls += __shfl_down(ls, off); }
    if((t & 63) == 0){ rb[t >> 6] = s; rl[t >> 6] = ls; }
    __syncthreads();
    if(t == 0){
        float denom = rb[0]+rb[1]+rb[2]+rb[3];
        if(denom < 1.f) denom = 1.f;
        out[256] = (rl[0]+rl[1]+rl[2]+rl[3]) / denom;
    }
}

extern "C" void kernel_launch(void* const* d_in, const int* in_sizes, int n_in,
                              void* d_out, int out_size, void* d_ws, size_t ws_size,
                              hipStream_t stream){
    const float* px    = (const float*)d_in[0];
    const float* vmask = (const float*)d_in[1];
    const int*   bins  = (const int*)d_in[2];
    const int*   tdiff = (const int*)d_in[3];
    const float* eps   = (const float*)d_in[4];
    const float* z0    = (const float*)d_in[5];
    const float* noise = (const float*)d_in[6];
    const float* Wv    = (const float*)d_in[7];
    const float* bemb  = (const float*)d_in[8];
    const float* Wih   = (const float*)d_in[9];
    const float* Whh   = (const float*)d_in[10];
    const float* bih   = (const float*)d_in[11];
    const float* bhh   = (const float*)d_in[12];
    const float* Wcls  = (const float*)d_in[13];
    const float* bcls  = (const float*)d_in[14];
    const float* Wproj = (const float*)d_in[15];
    const float* temb  = (const float*)d_in[16];
    const float* Wf    = (const float*)d_in[17];
    const float* bfu   = (const float*)d_in[18];
    const float* We1   = (const float*)d_in[19];
    const float* be1   = (const float*)d_in[20];
    const float* We2   = (const float*)d_in[21];
    const float* be2   = (const float*)d_in[22];
    float* out = (float*)d_out;

    float* ws      = (float*)d_ws;
    float* WT      = ws;                 // 1,048,576
    float* v       = ws + 1048576;       // 1,048,576
    float* vsyn    = ws + 2097152;       // 1,048,576
    float* hp      = ws + 3145728;       // 1,048,576
    float* partial = ws + 4194304;       // 512

    hipLaunchKernelGGL(k_transpose_wv, dim3(V_/16), dim3(256), 0, stream, Wv, WT);
    hipLaunchKernelGGL(k_visit_embed, dim3(NROW), dim3(256), 0, stream, px, vmask, bins, bemb, WT, v);
    hipLaunchKernelGGL((k_lstm_fused<true>), dim3(B_/16), dim3(512), 0, stream,
                       v, Whh, Wih, bih, bhh, Wproj, Wcls, bcls, vmask, hp, out);
    hipLaunchKernelGGL(k_drg, dim3(NROW/16), dim3(256), 0, stream,
                       v, hp, eps, tdiff, vmask, z0, noise, temb, Wf, bfu,
                       We1, be1, We2, be2, partial, vsyn);
    hipLaunchKernelGGL((k_lstm_fused<false>), dim3(B_/16), dim3(512), 0, stream,
                       vsyn, Whh, Wih, bih, bhh, Wproj, Wcls, bcls, vmask, (float*)nullptr, out + 128);
    hipLaunchKernelGGL(k_finalize, dim3(1), dim3(256), 0, stream, partial, vmask, out);
}

// Round 2
// 819.873 us; speedup vs baseline: 1.0052x; 1.0052x over previous
//
#include <hip/hip_runtime.h>

#define B_ 128
#define L_ 64
#define V_ 8192
#define E_ 128
#define H_ 128
#define NROW (B_*L_)
#define HSTRIDE 136
#define AS 136
#define XS 264
#define YS 136
#define ZS 132

typedef unsigned short u16;
typedef __attribute__((ext_vector_type(8))) short bf16x8;
typedef __attribute__((ext_vector_type(4))) float f32x4;

__device__ __forceinline__ float sigm(float x){ return 1.f/(1.f + __expf(-x)); }
__device__ __forceinline__ float ftanh(float x){ float e = __expf(2.f*x); return 1.f - 2.f/(e + 1.f); }
__device__ __forceinline__ u16 f2bf(float f){
    union { unsigned int i; float f; } x; x.f = f;
    unsigned int r = x.i + 0x7fff + ((x.i >> 16) & 1);
    return (u16)(r >> 16);
}
// raw barrier: LDS-only sync, no vmcnt drain (global loads/stores stay in flight)
#define LBAR() asm volatile("s_waitcnt lgkmcnt(0)\ns_barrier" ::: "memory")

__device__ __forceinline__ bf16x8 pack8(const float* p){
    const float4* q = (const float4*)p;
    float4 a = q[0], b = q[1];
    bf16x8 f;
    f[0]=(short)f2bf(a.x); f[1]=(short)f2bf(a.y); f[2]=(short)f2bf(a.z); f[3]=(short)f2bf(a.w);
    f[4]=(short)f2bf(b.x); f[5]=(short)f2bf(b.y); f[6]=(short)f2bf(b.z); f[7]=(short)f2bf(b.w);
    return f;
}

// ---------------------------------------------------------------- transpose W_visit [E,V] -> WT [V,E]
__global__ __launch_bounds__(256) void k_transpose_wv(const float* __restrict__ Wv, float* __restrict__ WT){
    __shared__ float tile[16][129];
    int v0 = blockIdx.x * 16;
    int t = threadIdx.x;
    #pragma unroll
    for(int i=0;i<8;i++){
        int idx = i*256 + t; int e = idx >> 4; int vv = idx & 15;
        tile[vv][e] = Wv[(size_t)e*V_ + v0 + vv];
    }
    __syncthreads();
    #pragma unroll
    for(int i=0;i<8;i++){
        int idx = i*256 + t; int vv = idx >> 7; int e = idx & 127;
        WT[(size_t)(v0+vv)*E_ + e] = tile[vv][e];
    }
}

// ---------------------------------------------------------------- v = (x @ Wv^T + bin_embed[delta]) * m
__global__ __launch_bounds__(256) void k_visit_embed(const float* __restrict__ px, const float* __restrict__ vmask,
                                                     const int* __restrict__ bins, const float* __restrict__ bemb,
                                                     const float* __restrict__ WT, float* __restrict__ v){
    __shared__ int idxs[512];
    __shared__ int cnt;
    __shared__ int dsh;
    __shared__ float msh;
    __shared__ float4 red[8][32];
    int row = blockIdx.x; int l = row & 63;
    int t = threadIdx.x;
    if(t==0){
        cnt = 0;
        float m = vmask[row];
        int d = 0;
        if(l > 0){ d = bins[row] - bins[row-1]; d = d < 0 ? 0 : (d > 513 ? 513 : d); }
        if(!(m > 0.f)) d = 0;
        dsh = d; msh = m;
    }
    __syncthreads();
    const uint4* xr4 = (const uint4*)(px + (size_t)row * V_);
    for(int i=t;i<2048;i+=256){
        uint4 u = xr4[i];
        unsigned int w[4] = {u.x,u.y,u.z,u.w};
        #pragma unroll
        for(int j=0;j<4;j++){
            if(w[j]){ int p = atomicAdd(&cnt,1); if(p<512) idxs[p] = i*4 + j; }
        }
    }
    __syncthreads();
    int n = cnt; if(n > 512) n = 512;
    int eq = t & 31, jg = t >> 5;
    float4 a4 = {0.f,0.f,0.f,0.f};
    for(int j=jg;j<n;j+=8){
        const float4* wr = (const float4*)(WT + (size_t)idxs[j]*E_);
        float4 wv = wr[eq];
        a4.x += wv.x; a4.y += wv.y; a4.z += wv.z; a4.w += wv.w;
    }
    red[jg][eq] = a4;
    __syncthreads();
    if(t < 32){
        float4 s = red[0][t];
        #pragma unroll
        for(int g=1;g<8;g++){
            float4 r = red[g][t];
            s.x += r.x; s.y += r.y; s.z += r.z; s.w += r.w;
        }
        const float4* bp = (const float4*)(bemb + dsh*E_);
        float4 bv = bp[t];
        float m = msh;
        float4 o;
        o.x = (s.x + bv.x)*m; o.y = (s.y + bv.y)*m; o.z = (s.z + bv.z)*m; o.w = (s.w + bv.w)*m;
        ((float4*)(v + (size_t)row*E_))[t] = o;
    }
}

// ---------------------------------------------------------------- LSTM fused: on-the-fly input GEMM + recurrence + hp + logits
template<bool DOHP>
__device__ __forceinline__ void lstm_step(int l,
        const u16* __restrict__ bufr, u16* __restrict__ bufw,
        const u16* __restrict__ vbr, u16* __restrict__ vbw,
        const float*& pv, float*& hpb,
        const bf16x8 (&bfh)[4][4], const bf16x8 (&bfv)[4][4], const bf16x8 (&wp)[4],
        const float (&bb)[4], float (&c4)[4], float (&lg4)[4], const int (&len4)[4],
        float wcv, int t, int lc, int quad, int cw){
    // issue v-prefetch for step l+1 first (longest latency; L2/L3-resident)
    float4 vnx;
    if(l+1 < 64){ vnx = *(const float4*)pv; pv += E_; }
    bf16x8 afh[4], afv[4];
    #pragma unroll
    for(int kt=0;kt<4;kt++){
        afh[kt] = *(const bf16x8*)&bufr[lc*HSTRIDE + kt*32 + quad*8];
        afv[kt] = *(const bf16x8*)&vbr[lc*AS + kt*32 + quad*8];
    }
    f32x4 acc[4], acch;
    #pragma unroll
    for(int g=0;g<4;g++) acc[g] = (f32x4){0.f,0.f,0.f,0.f};
    acch = (f32x4){0.f,0.f,0.f,0.f};
    #pragma unroll
    for(int kt=0;kt<4;kt++){
        #pragma unroll
        for(int g=0;g<4;g++){
            acc[g] = __builtin_amdgcn_mfma_f32_16x16x32_bf16(afh[kt], bfh[g][kt], acc[g], 0,0,0);
            acc[g] = __builtin_amdgcn_mfma_f32_16x16x32_bf16(afv[kt], bfv[g][kt], acc[g], 0,0,0);
        }
        if constexpr (DOHP)
            acch = __builtin_amdgcn_mfma_f32_16x16x32_bf16(afh[kt], wp[kt], acch, 0,0,0);
    }
    if constexpr (DOHP){
        // hp[b,l] = h_{l-1} @ Wproj^T  (af IS h_{l-1}; h=0 at l=0 -> hp=0).
        // Mask multiply dropped: masked-row hp never reaches a checked output
        // (loss re-masks with mrow, z-updates re-mask with m, logits index < len).
        #pragma unroll
        for(int r=0;r<4;r++) hpb[(size_t)r*64*E_] = acch[r];
        hpb += E_;
    }
    #pragma unroll
    for(int r=0;r<4;r++){
        float gi = acc[0][r] + bb[0];
        float gf = acc[1][r] + bb[1];
        float gg = acc[2][r] + bb[2];
        float go = acc[3][r] + bb[3];
        float c  = sigm(gf)*c4[r] + sigm(gi)*ftanh(gg);
        float h  = sigm(go)*ftanh(c);
        c4[r] = c;
        bufw[(quad*4+r)*HSTRIDE + cw] = f2bf(h);
        if(l == len4[r]-1) lg4[r] += h * wcv;
    }
    // stage prefetched v row-block for l+1 into the other LDS buffer
    if(l+1 < 64){
        int sr = t >> 5, se = (t & 31)*4;
        u16* d = vbw + sr*AS + se;
        d[0]=f2bf(vnx.x); d[1]=f2bf(vnx.y); d[2]=f2bf(vnx.z); d[3]=f2bf(vnx.w);
    }
    LBAR();
}

// __launch_bounds__(512,1): grid is only 8 blocks on 256 CUs, so >1 block/CU never
// happens anyway; the previous (512,2) capped VGPRs at 128 while the loop-resident
// working set (bfh+bfv+wp+acc+frags ~225 VGPR) needs ~256 -> ~100 VGPRs were spilled
// and reloaded from scratch EVERY serial step (VGPR_Count=128, 5.5 MB scratch writes
// on the no-hp variant, 6180 cyc/step). (512,1) -> 256-VGPR cap, zero spills.
template<bool DOHP>
__global__ __launch_bounds__(512,1) void k_lstm_fused(const float* __restrict__ vin,
        const float* __restrict__ Whh, const float* __restrict__ Wih,
        const float* __restrict__ bih, const float* __restrict__ bhh,
        const float* __restrict__ Wproj, const float* __restrict__ Wcls, const float* __restrict__ bcls,
        const float* __restrict__ vmask, float* __restrict__ hp_out, float* __restrict__ logits_out){
    __shared__ __align__(16) u16 hbuf[2][16*HSTRIDE];
    __shared__ __align__(16) u16 vbuf[2][16*AS];
    __shared__ float vmsh[16*64];
    __shared__ int lensh[16];
    __shared__ float lgsh[16][132];
    int t = threadIdx.x;
    int wave = t >> 6, lane = t & 63;
    int quad = lane >> 4, lc = lane & 15;
    int cw = wave*16 + lc;
    int b0 = blockIdx.x * 16;

    for(int i=t;i<16*HSTRIDE;i+=512) hbuf[0][i] = 0;
    for(int i=t;i<1024;i+=512) vmsh[i] = vmask[b0*64 + i];
    // stage v for l=0; pv then points at this thread's l=1 element
    const float* pv = vin + (size_t)(b0 + (t>>5))*64*E_ + (t&31)*4;
    {
        float4 v0 = *(const float4*)pv; pv += E_;
        u16* d = &vbuf[0][(t>>5)*AS + (t&31)*4];
        d[0]=f2bf(v0.x); d[1]=f2bf(v0.y); d[2]=f2bf(v0.z); d[3]=f2bf(v0.w);
    }
    __syncthreads();
    if(t < 16){
        int s = 0;
        #pragma unroll
        for(int i=0;i<64;i++) s += (vmsh[t*64 + i] > 0.f) ? 1 : 0;
        lensh[t] = s < 1 ? 1 : s;
    }

    bf16x8 bfh[4][4], bfv[4][4], wp[4];
    float bb[4];
    #pragma unroll
    for(int g=0;g<4;g++){
        int n = g*128 + cw;
        bb[g] = bih[n] + bhh[n];
        const float* wrh = Whh + (size_t)n*H_ + quad*8;
        const float* wrv = Wih + (size_t)n*E_ + quad*8;
        #pragma unroll
        for(int kt=0;kt<4;kt++){ bfh[g][kt] = pack8(wrh + kt*32); bfv[g][kt] = pack8(wrv + kt*32); }
    }
    if constexpr (DOHP){
        const float* wr = Wproj + (size_t)cw*H_ + quad*8;
        #pragma unroll
        for(int kt=0;kt<4;kt++) wp[kt] = pack8(wr + kt*32);
    }
    float wcv = Wcls[cw];
    float c4[4] = {0.f,0.f,0.f,0.f};
    float lg4[4] = {0.f,0.f,0.f,0.f};
    float* hpb = DOHP ? (hp_out + (size_t)(b0 + quad*4)*64*E_ + cw) : nullptr;
    __syncthreads();
    int len4[4];
    #pragma unroll
    for(int r=0;r<4;r++) len4[r] = lensh[quad*4 + r];

    for(int lb=0;lb<64;lb+=2){
        lstm_step<DOHP>(lb,   hbuf[0], hbuf[1], vbuf[0], vbuf[1], pv, hpb, bfh, bfv, wp, bb, c4, lg4, len4, wcv, t, lc, quad, cw);
        lstm_step<DOHP>(lb+1, hbuf[1], hbuf[0], vbuf[1], vbuf[0], pv, hpb, bfh, bfv, wp, bb, c4, lg4, len4, wcv, t, lc, quad, cw);
    }
    #pragma unroll
    for(int r=0;r<4;r++) lgsh[quad*4+r][cw] = lg4[r];
    __syncthreads();
    {
        int row = t >> 5, l32 = t & 31;
        float s = lgsh[row][l32] + lgsh[row][l32+32] + lgsh[row][l32+64] + lgsh[row][l32+96];
        s += __shfl_down(s, 16, 32);
        s += __shfl_down(s, 8, 32);
        s += __shfl_down(s, 4, 32);
        s += __shfl_down(s, 2, 32);
        s += __shfl_down(s, 1, 32);
        if(l32 == 0) logits_out[b0 + row] = s + bcls[0];
    }
}

// ---------------------------------------------------------------- fused: diff_loss + reverse diffusion -> v_syn
__global__ __launch_bounds__(256,2) void k_drg(const float* __restrict__ v, const float* __restrict__ hp,
        const float* __restrict__ eps, const int* __restrict__ tdiff, const float* __restrict__ vmask,
        const float* __restrict__ z0, const float* __restrict__ noise, const float* __restrict__ temb,
        const float* __restrict__ Wf, const float* __restrict__ bfu,
        const float* __restrict__ We1, const float* __restrict__ be1,
        const float* __restrict__ We2, const float* __restrict__ be2,
        float* __restrict__ partial, float* __restrict__ vsyn){
    __shared__ __align__(16) float zbuf[16*ZS];
    __shared__ float hpbuf[16*ZS];
    __shared__ __align__(16) u16 xbuf[16*XS];
    __shared__ __align__(16) u16 y1buf[16*YS];
    __shared__ float wfsh[512];
    __shared__ float ssh[16][2], hpd[16][2];
    __shared__ float mrow[16]; __shared__ int trow[16];
    __shared__ float sbeta[10], sabar[10];
    __shared__ float rb[4];
    int row0 = blockIdx.x * 16; int t = threadIdx.x;
    int wave = t >> 6, lane = t & 63, quad = lane >> 4, lc = lane & 15;

    if(t==0){
        float p = 1.f;
        for(int k=0;k<10;k++){ float b = 1e-4f + (0.02f - 1e-4f)*k/9.f; sbeta[k] = b; p *= (1.f - b); sabar[k] = p; }
    }
    if(t < 16){
        int row = row0 + t; float m = vmask[row];
        mrow[t] = m; trow[t] = (m > 0.f) ? tdiff[row >> 6] : 1;
    }
    for(int i=t;i<512;i+=256) wfsh[i] = Wf[i];
    __syncthreads();
    // z_t (diffusion-loss forward sample) and hp into LDS
    #pragma unroll
    for(int i=0;i<8;i++){
        int flat = i*256 + t; int r = flat >> 7; int e = flat & 127; int row = row0 + r;
        float ab = sabar[trow[r]-1];
        zbuf[r*ZS + e] = (sqrtf(ab)*v[(size_t)row*E_ + e] + sqrtf(1.f - ab)*eps[(size_t)row*E_ + e]) * mrow[r];
        hpbuf[r*ZS + e] = hp[(size_t)row*E_ + e];
    }
    bf16x8 wf1[2][8], wf2[2][4];
    float be1v[2], be2v[2];
    #pragma unroll
    for(int nt=0;nt<2;nt++){
        int n = wave*32 + nt*16 + lc;
        be1v[nt] = be1[n]; be2v[nt] = be2[n];
        const float* w1 = We1 + (size_t)n*256 + quad*8;
        #pragma unroll
        for(int kt=0;kt<8;kt++) wf1[nt][kt] = pack8(w1 + kt*32);
        const float* w2 = We2 + (size_t)n*128 + quad*8;
        #pragma unroll
        for(int kt=0;kt<4;kt++) wf2[nt][kt] = pack8(w2 + kt*32);
    }
    __syncthreads();
    // hp·Wf[:,128:256]+bfu (reused by both diff and all 10 reverse steps)
    {
        int row = t >> 4, k = (t >> 3) & 1, sub = t & 7;
        float p = 0.f;
        #pragma unroll
        for(int i=0;i<16;i++)
            p += hpbuf[row*ZS + sub*16 + i] * wfsh[k*256 + 128 + sub*16 + i];
        p += __shfl_down(p,4); p += __shfl_down(p,2); p += __shfl_down(p,1);
        if(sub == 0) hpd[row][k] = p + bfu[k];
    }
    __syncthreads();

    // ---------- 11 fuse_eps evaluations: s=0 -> diff loss on z_t; s=1..10 -> reverse steps
    for(int s=0;s<11;s++){
        int kk = 11 - s;                // reverse step index for s>=1
        // prefetch this iteration's global inputs early (hidden under dot+MFMA phases)
        float nzv[8], epv[8], z0v[8];
        if(s >= 1){
            #pragma unroll
            for(int nt=0;nt<2;nt++)
                #pragma unroll
                for(int r=0;r<4;r++)
                    nzv[nt*4+r] = noise[((size_t)(s-1)*NROW + row0 + quad*4 + r)*E_ + wave*32 + nt*16 + lc];
        } else {
            #pragma unroll
            for(int nt=0;nt<2;nt++)
                #pragma unroll
                for(int r=0;r<4;r++)
                    epv[nt*4+r] = eps[(size_t)(row0 + quad*4 + r)*E_ + wave*32 + nt*16 + lc];
            #pragma unroll
            for(int i=0;i<8;i++){
                int flat = i*256 + t;
                z0v[i] = z0[(size_t)(row0 + (flat >> 7))*E_ + (flat & 127)];
            }
        }
        {
            int row = t >> 4, k = (t >> 3) & 1, sub = t & 7;
            float q = 0.f;
            #pragma unroll
            for(int i=0;i<16;i++)
                q += zbuf[row*ZS + sub*16 + i] * wfsh[k*256 + sub*16 + i];
            q += __shfl_down(q,4); q += __shfl_down(q,2); q += __shfl_down(q,1);
            if(sub == 0) ssh[row][k] = q + hpd[row][k];
        }
        __syncthreads();
        {
            int row = t >> 4, c0 = (t & 15) * 16;
            float s0 = ssh[row][0], s1 = ssh[row][1];
            float a0 = 1.f/(1.f + __expf(s1 - s0)), a1 = 1.f - a0;
            int tt = (s == 0) ? trow[row] : ((mrow[row] > 0.f) ? kk : 1);
            #pragma unroll
            for(int i=0;i<16;i++){
                int c = c0 + i;
                float val = (c < 128) ? (a0*zbuf[row*ZS + c] + a1*hpbuf[row*ZS + c])
                                      : temb[tt*E_ + (c - 128)];
                xbuf[row*XS + c] = f2bf(val);
            }
        }
        __syncthreads();
        f32x4 acc1[2];
        acc1[0] = (f32x4){0.f,0.f,0.f,0.f}; acc1[1] = (f32x4){0.f,0.f,0.f,0.f};
        #pragma unroll
        for(int kt=0;kt<8;kt++){
            bf16x8 af = *(const bf16x8*)&xbuf[lc*XS + kt*32 + quad*8];
            acc1[0] = __builtin_amdgcn_mfma_f32_16x16x32_bf16(af, wf1[0][kt], acc1[0], 0,0,0);
            acc1[1] = __builtin_amdgcn_mfma_f32_16x16x32_bf16(af, wf1[1][kt], acc1[1], 0,0,0);
        }
        #pragma unroll
        for(int nt=0;nt<2;nt++){
            #pragma unroll
            for(int r=0;r<4;r++)
                y1buf[(quad*4+r)*YS + wave*32 + nt*16 + lc] = f2bf(fmaxf(acc1[nt][r] + be1v[nt], 0.f));
        }
        __syncthreads();
        f32x4 acc2[2];
        acc2[0] = (f32x4){0.f,0.f,0.f,0.f}; acc2[1] = (f32x4){0.f,0.f,0.f,0.f};
        #pragma unroll
        for(int kt=0;kt<4;kt++){
            bf16x8 af = *(const bf16x8*)&y1buf[lc*YS + kt*32 + quad*8];
            acc2[0] = __builtin_amdgcn_mfma_f32_16x16x32_bf16(af, wf2[0][kt], acc2[0], 0,0,0);
            acc2[1] = __builtin_amdgcn_mfma_f32_16x16x32_bf16(af, wf2[1][kt], acc2[1], 0,0,0);
        }
        if(s == 0){
            // diffusion loss partial; then load z0 (prefetched) for the reverse chain
            float lp = 0.f;
            #pragma unroll
            for(int nt=0;nt<2;nt++){
                #pragma unroll
                for(int r=0;r<4;r++){
                    int m = quad*4 + r;
                    float d = (acc2[nt][r] + be2v[nt]) - epv[nt*4+r];
                    lp += d*d*mrow[m];
                }
            }
            #pragma unroll
            for(int off=32;off;off>>=1) lp += __shfl_down(lp, off);
            if(lane == 0) rb[wave] = lp;
            __syncthreads();
            if(t == 0) partial[blockIdx.x] = rb[0]+rb[1]+rb[2]+rb[3];
            #pragma unroll
            for(int i=0;i<8;i++){
                int flat = i*256 + t; int r = flat >> 7; int e = flat & 127;
                zbuf[r*ZS + e] = z0v[i];
            }
            __syncthreads();
        } else {
            float beta = sbeta[kk-1];
            float c1 = beta / sqrtf(1.f - sabar[kk-1]);
            float c2 = 1.f / sqrtf(1.f - beta);
            float sb = sqrtf(beta);
            #pragma unroll
            for(int nt=0;nt<2;nt++){
                int n = wave*32 + nt*16 + lc;
                #pragma unroll
                for(int r=0;r<4;r++){
                    int m = quad*4 + r;
                    float e = acc2[nt][r] + be2v[nt];
                    float z = zbuf[m*ZS + n];
                    float mean = (z - c1*e) * c2;
                    float nz = nzv[nt*4+r];
                    float znew = (kk > 1) ? (mean + sb*nz) : mean;
                    zbuf[m*ZS + n] = znew * mrow[m];
                }
            }
            __syncthreads();
        }
    }
    // ---------- write v_syn (final zbuf) as f32; lstm2 computes its input GEMM on the fly
    {
        int r = t >> 4, e0 = (t & 15) * 8;
        float4 a = *(const float4*)&zbuf[r*ZS + e0];
        float4 b2 = *(const float4*)&zbuf[r*ZS + e0 + 4];
        *(float4*)&vsyn[(size_t)(row0 + r)*E_ + e0] = a;
        *(float4*)&vsyn[(size_t)(row0 + r)*E_ + e0 + 4] = b2;
    }
}

// ---------------------------------------------------------------- loss finalize (sums 512 partials + mask)
__global__ void k_finalize(const float* __restrict__ partial, const float* __restrict__ vmask, float* __restrict__ out){
    __shared__ float rb[4], rl[4];
    int t = threadIdx.x;
    float s = 0.f;
    for(int i=t;i<NROW;i+=256) s += vmask[i];
    float ls = 0.f;
    for(int i=t;i<512;i+=256) ls += partial[i];
    #pragma unroll
    for(int off=32;off;off>>=1){ s += __shfl_down(s, off); ls += __shfl_down(ls, off); }
    if((t & 63) == 0){ rb[t >> 6] = s; rl[t >> 6] = ls; }
    __syncthreads();
    if(t == 0){
        float denom = rb[0]+rb[1]+rb[2]+rb[3];
        if(denom < 1.f) denom = 1.f;
        out[256] = (rl[0]+rl[1]+rl[2]+rl[3]) / denom;
    }
}

extern "C" void kernel_launch(void* const* d_in, const int* in_sizes, int n_in,
                              void* d_out, int out_size, void* d_ws, size_t ws_size,
                              hipStream_t stream){
    const float* px    = (const float*)d_in[0];
    const float* vmask = (const float*)d_in[1];
    const int*   bins  = (const int*)d_in[2];
    const int*   tdiff = (const int*)d_in[3];
    const float* eps   = (const float*)d_in[4];
    const float* z0    = (const float*)d_in[5];
    const float* noise = (const float*)d_in[6];
    const float* Wv    = (const float*)d_in[7];
    const float* bemb  = (const float*)d_in[8];
    const float* Wih   = (const float*)d_in[9];
    const float* Whh   = (const float*)d_in[10];
    const float* bih   = (const float*)d_in[11];
    const float* bhh   = (const float*)d_in[12];
    const float* Wcls  = (const float*)d_in[13];
    const float* bcls  = (const float*)d_in[14];
    const float* Wproj = (const float*)d_in[15];
    const float* temb  = (const float*)d_in[16];
    const float* Wf    = (const float*)d_in[17];
    const float* bfu   = (const float*)d_in[18];
    const float* We1   = (const float*)d_in[19];
    const float* be1   = (const float*)d_in[20];
    const float* We2   = (const float*)d_in[21];
    const float* be2   = (const float*)d_in[22];
    float* out = (float*)d_out;

    float* ws      = (float*)d_ws;
    float* WT      = ws;                 // 1,048,576
    float* v       = ws + 1048576;       // 1,048,576
    float* vsyn    = ws + 2097152;       // 1,048,576
    float* hp      = ws + 3145728;       // 1,048,576
    float* partial = ws + 4194304;       // 512

    hipLaunchKernelGGL(k_transpose_wv, dim3(V_/16), dim3(256), 0, stream, Wv, WT);
    hipLaunchKernelGGL(k_visit_embed, dim3(NROW), dim3(256), 0, stream, px, vmask, bins, bemb, WT, v);
    hipLaunchKernelGGL((k_lstm_fused<true>), dim3(B_/16), dim3(512), 0, stream,
                       v, Whh, Wih, bih, bhh, Wproj, Wcls, bcls, vmask, hp, out);
    hipLaunchKernelGGL(k_drg, dim3(NROW/16), dim3(256), 0, stream,
                       v, hp, eps, tdiff, vmask, z0, noise, temb, Wf, bfu,
                       We1, be1, We2, be2, partial, vsyn);
    hipLaunchKernelGGL((k_lstm_fused<false>), dim3(B_/16), dim3(512), 0, stream,
                       vsyn, Whh, Wih, bih, bhh, Wproj, Wcls, bcls, vmask, (float*)nullptr, out + 128);
    hipLaunchKernelGGL(k_finalize, dim3(1), dim3(256), 0, stream, partial, vmask, out);
}

// Round 3
// 742.331 us; speedup vs baseline: 1.1102x; 1.1045x over previous
//
#include <hip/hip_runtime.h>

#define B_ 128
#define L_ 64
#define V_ 8192
#define E_ 128
#define H_ 128
#define NROW (B_*L_)
#define HSTRIDE 136
#define AS 136
#define XS 264
#define YS 136
#define ZS 132
#define HS2 136

typedef unsigned short u16;
typedef __attribute__((ext_vector_type(8))) short bf16x8;
typedef __attribute__((ext_vector_type(4))) float f32x4;

__device__ __forceinline__ float sigm(float x){ return 1.f/(1.f + __expf(-x)); }
__device__ __forceinline__ float ftanh(float x){ float e = __expf(2.f*x); return 1.f - 2.f/(e + 1.f); }
__device__ __forceinline__ u16 f2bf(float f){
    union { unsigned int i; float f; } x; x.f = f;
    unsigned int r = x.i + 0x7fff + ((x.i >> 16) & 1);
    return (u16)(r >> 16);
}
// raw barrier: LDS-only sync, no vmcnt drain (global loads/stores stay in flight)
#define LBAR() asm volatile("s_waitcnt lgkmcnt(0)\ns_barrier" ::: "memory")

__device__ __forceinline__ bf16x8 pack8(const float* p){
    const float4* q = (const float4*)p;
    float4 a = q[0], b = q[1];
    bf16x8 f;
    f[0]=(short)f2bf(a.x); f[1]=(short)f2bf(a.y); f[2]=(short)f2bf(a.z); f[3]=(short)f2bf(a.w);
    f[4]=(short)f2bf(b.x); f[5]=(short)f2bf(b.y); f[6]=(short)f2bf(b.z); f[7]=(short)f2bf(b.w);
    return f;
}

// ---------------------------------------------------------------- transpose W_visit [E,V] -> WT [V,E]
__global__ __launch_bounds__(256) void k_transpose_wv(const float* __restrict__ Wv, float* __restrict__ WT){
    __shared__ float tile[16][129];
    int v0 = blockIdx.x * 16;
    int t = threadIdx.x;
    #pragma unroll
    for(int i=0;i<8;i++){
        int idx = i*256 + t; int e = idx >> 4; int vv = idx & 15;
        tile[vv][e] = Wv[(size_t)e*V_ + v0 + vv];
    }
    __syncthreads();
    #pragma unroll
    for(int i=0;i<8;i++){
        int idx = i*256 + t; int vv = idx >> 7; int e = idx & 127;
        WT[(size_t)(v0+vv)*E_ + e] = tile[vv][e];
    }
}

// ---------------------------------------------------------------- v = (x @ Wv^T + bin_embed[delta]) * m
__global__ __launch_bounds__(256) void k_visit_embed(const float* __restrict__ px, const float* __restrict__ vmask,
                                                     const int* __restrict__ bins, const float* __restrict__ bemb,
                                                     const float* __restrict__ WT, float* __restrict__ v){
    __shared__ int idxs[512];
    __shared__ int cnt;
    __shared__ int dsh;
    __shared__ float msh;
    __shared__ float4 red[8][32];
    int row = blockIdx.x; int l = row & 63;
    int t = threadIdx.x;
    if(t==0){
        cnt = 0;
        float m = vmask[row];
        int d = 0;
        if(l > 0){ d = bins[row] - bins[row-1]; d = d < 0 ? 0 : (d > 513 ? 513 : d); }
        if(!(m > 0.f)) d = 0;
        dsh = d; msh = m;
    }
    __syncthreads();
    const uint4* xr4 = (const uint4*)(px + (size_t)row * V_);
    for(int i=t;i<2048;i+=256){
        uint4 u = xr4[i];
        unsigned int w[4] = {u.x,u.y,u.z,u.w};
        #pragma unroll
        for(int j=0;j<4;j++){
            if(w[j]){ int p = atomicAdd(&cnt,1); if(p<512) idxs[p] = i*4 + j; }
        }
    }
    __syncthreads();
    int n = cnt; if(n > 512) n = 512;
    int eq = t & 31, jg = t >> 5;
    float4 a4 = {0.f,0.f,0.f,0.f};
    for(int j=jg;j<n;j+=8){
        const float4* wr = (const float4*)(WT + (size_t)idxs[j]*E_);
        float4 wv = wr[eq];
        a4.x += wv.x; a4.y += wv.y; a4.z += wv.z; a4.w += wv.w;
    }
    red[jg][eq] = a4;
    __syncthreads();
    if(t < 32){
        float4 s = red[0][t];
        #pragma unroll
        for(int g=1;g<8;g++){
            float4 r = red[g][t];
            s.x += r.x; s.y += r.y; s.z += r.z; s.w += r.w;
        }
        const float4* bp = (const float4*)(bemb + dsh*E_);
        float4 bv = bp[t];
        float m = msh;
        float4 o;
        o.x = (s.x + bv.x)*m; o.y = (s.y + bv.y)*m; o.z = (s.z + bv.z)*m; o.w = (s.w + bv.w)*m;
        ((float4*)(v + (size_t)row*E_))[t] = o;
    }
}

// ---------------------------------------------------------------- pack weights into per-wave bf16 MFMA fragments
// layout: groups of 512 u16; group=((w*NT+nt)*KT+kt); elem: lane*8+j; src n = w*WS + nt*TS + lc, k = kt*32+quad*8+j
__global__ __launch_bounds__(256) void k_pack(const float* __restrict__ Whh, const float* __restrict__ Wih,
                                              const float* __restrict__ We1, const float* __restrict__ We2,
                                              const float* __restrict__ Wproj,
                                              u16* __restrict__ dWhh, u16* __restrict__ dWih,
                                              u16* __restrict__ dWe1, u16* __restrict__ dWe2,
                                              u16* __restrict__ dWproj){
    int bid = blockIdx.x; int t = threadIdx.x;
    const float* src; u16* dst; int WS,TS,NT,KT,K; int base;
    if(bid<32){ src=Whh; dst=dWhh; WS=16; TS=128; NT=4; KT=4; K=128; base=bid; }
    else if(bid<64){ src=Wih; dst=dWih; WS=128; TS=16; NT=8; KT=4; K=128; base=bid-32; }
    else if(bid<80){ src=We1; dst=dWe1; WS=32; TS=16; NT=2; KT=8; K=256; base=bid-64; }
    else if(bid<88){ src=We2; dst=dWe2; WS=32; TS=16; NT=2; KT=4; K=128; base=bid-80; }
    else { src=Wproj; dst=dWproj; WS=32; TS=16; NT=2; KT=4; K=128; base=bid-88; }
    for(int i=0;i<8;i++){
        int o = base*2048 + i*256 + t;
        int g = o >> 9; int lane = (o >> 3) & 63; int j = o & 7;
        int kt = g % KT; int r2 = g / KT; int nt = r2 % NT; int w = r2 / NT;
        int lc = lane & 15; int quad = lane >> 4;
        int n = w*WS + nt*TS + lc; int k = kt*32 + quad*8 + j;
        dst[o] = f2bf(src[(size_t)n*K + k]);
    }
}

// ---------------------------------------------------------------- xg = A @ Wih^T + b, stored lstm-thread-major
// block = (bg, l): rows (bg*16+rr, l). out slab [bid][512 thr][16 floats]: t*16 + g*4 + r
__global__ __launch_bounds__(256,2) void k_gemm_xgp(const float* __restrict__ A, const u16* __restrict__ Wihp,
                                                    const float* __restrict__ bih, const float* __restrict__ bhh,
                                                    float* __restrict__ xgp){
    __shared__ __align__(16) u16 abuf[16*AS];
    int t = threadIdx.x, wave = t >> 6, lane = t & 63, quad = lane >> 4, lc = lane & 15;
    int bid = blockIdx.x; int bg = bid >> 6, l = bid & 63;
    #pragma unroll
    for(int i=0;i<8;i++){
        int flat = i*256 + t; int r = flat >> 7, e = flat & 127;
        abuf[r*AS + e] = f2bf(A[((size_t)(bg*16+r)*64 + l)*E_ + e]);
    }
    bf16x8 wg[8][4]; float bb[8];
    #pragma unroll
    for(int nt=0;nt<8;nt++){
        int n = wave*128 + nt*16 + lc;
        bb[nt] = bih[n] + bhh[n];
        #pragma unroll
        for(int kt=0;kt<4;kt++)
            wg[nt][kt] = *(const bf16x8*)(Wihp + (((wave*8+nt)*4+kt)<<9) + lane*8);
    }
    __syncthreads();
    f32x4 ac[8];
    #pragma unroll
    for(int nt=0;nt<8;nt++) ac[nt] = (f32x4){0.f,0.f,0.f,0.f};
    #pragma unroll
    for(int kt=0;kt<4;kt++){
        bf16x8 af = *(const bf16x8*)&abuf[lc*AS + kt*32 + quad*8];
        #pragma unroll
        for(int nt=0;nt<8;nt++)
            ac[nt] = __builtin_amdgcn_mfma_f32_16x16x32_bf16(af, wg[nt][kt], ac[nt], 0,0,0);
    }
    float* dst = xgp + (size_t)bid*8192;
    #pragma unroll
    for(int nt=0;nt<8;nt++){
        float4 o;
        o.x = ac[nt][0] + bb[nt]; o.y = ac[nt][1] + bb[nt];
        o.z = ac[nt][2] + bb[nt]; o.w = ac[nt][3] + bb[nt];
        *(float4*)(dst + nt*1024 + quad*256 + lc*16 + wave*4) = o;
    }
}

// ---------------------------------------------------------------- LSTM: recurrence only (xg precomputed) + logits
template<bool STOREH>
__device__ __forceinline__ void lstm_step(int l,
        const u16* __restrict__ bufr, u16* __restrict__ bufw,
        const f32x4*& pxg, u16* hsp,
        const bf16x8 (&bfh)[4][4],
        f32x4 (&xc)[4], f32x4 (&xn)[4], float (&c4)[4], float (&lg4)[4],
        const int (&len4)[4], float wcv, int lc, int quad, int cw){
    // prefetch next step's xg (4 contiguous float4s per thread)
    if(l+1 < 64){
        #pragma unroll
        for(int g=0;g<4;g++) xn[g] = pxg[g];
        pxg += 2048;
    }
    bf16x8 afh[4];
    #pragma unroll
    for(int kt=0;kt<4;kt++)
        afh[kt] = *(const bf16x8*)&bufr[lc*HSTRIDE + kt*32 + quad*8];
    f32x4 acc[4];
    #pragma unroll
    for(int g=0;g<4;g++) acc[g] = (f32x4){0.f,0.f,0.f,0.f};
    #pragma unroll
    for(int kt=0;kt<4;kt++){
        #pragma unroll
        for(int g=0;g<4;g++)
            acc[g] = __builtin_amdgcn_mfma_f32_16x16x32_bf16(afh[kt], bfh[g][kt], acc[g], 0,0,0);
    }
    #pragma unroll
    for(int r=0;r<4;r++){
        float gi = acc[0][r] + xc[0][r];
        float gf = acc[1][r] + xc[1][r];
        float gg = acc[2][r] + xc[2][r];
        float go = acc[3][r] + xc[3][r];
        float c  = sigm(gf)*c4[r] + sigm(gi)*ftanh(gg);
        float h  = sigm(go)*ftanh(c);
        c4[r] = c;
        u16 hb = f2bf(h);
        bufw[(quad*4+r)*HSTRIDE + cw] = hb;
        if constexpr (STOREH) hsp[(size_t)r*8192 + (size_t)l*128] = hb;
        if(l == len4[r]-1) lg4[r] += h * wcv;
    }
    LBAR();
}

// grid = 8 blocks on 256 CUs -> occupancy is irrelevant; waves_per_eu(2,2) tells the
// scheduler its pressure target is 2 waves/SIMD (256 VGPR budget) so the ~150-VGPR
// loop-resident set (bfh 64 + xg dbuf 32 + acc/frags) stays resident. Weight frags
// are plain loads from pre-packed bf16 (k_pack) -> even if rematerialized, it's one
// L2-hit dwordx4, not a 48-VALU f32->bf16 repack.
template<bool STOREH>
__global__ __attribute__((amdgpu_waves_per_eu(2,2))) __launch_bounds__(512)
void k_lstm(const float* __restrict__ xgp, const u16* __restrict__ Whhp,
            const float* __restrict__ Wcls, const float* __restrict__ bcls,
            const float* __restrict__ vmask, u16* __restrict__ h_store,
            float* __restrict__ logits_out){
    __shared__ __align__(16) u16 hbuf[2][16*HSTRIDE];
    __shared__ float vmsh[16*64];
    __shared__ int lensh[16];
    __shared__ float lgsh[16][132];
    int t = threadIdx.x;
    int wave = t >> 6, lane = t & 63;
    int quad = lane >> 4, lc = lane & 15;
    int cw = wave*16 + lc;
    int bg = blockIdx.x; int b0 = bg * 16;

    for(int i=t;i<16*HSTRIDE;i+=512) hbuf[0][i] = 0;
    for(int i=t;i<1024;i+=512) vmsh[i] = vmask[b0*64 + i];
    __syncthreads();
    if(t < 16){
        int s = 0;
        #pragma unroll
        for(int i=0;i<64;i++) s += (vmsh[t*64 + i] > 0.f) ? 1 : 0;
        lensh[t] = s < 1 ? 1 : s;
    }

    bf16x8 bfh[4][4];
    #pragma unroll
    for(int g=0;g<4;g++)
        #pragma unroll
        for(int kt=0;kt<4;kt++)
            bfh[g][kt] = *(const bf16x8*)(Whhp + (((wave*4+g)*4+kt)<<9) + lane*8);
    float wcv = Wcls[cw];
    float c4[4] = {0.f,0.f,0.f,0.f};
    float lg4[4] = {0.f,0.f,0.f,0.f};
    u16* hsp = STOREH ? (h_store + ((size_t)(b0 + quad*4)*64)*128 + cw) : (u16*)nullptr;

    const f32x4* pxg = (const f32x4*)(xgp + (size_t)bg*64*8192) + t*4;
    f32x4 x0[4], x1[4];
    #pragma unroll
    for(int g=0;g<4;g++) x0[g] = pxg[g];
    pxg += 2048;
    __syncthreads();
    int len4[4];
    #pragma unroll
    for(int r=0;r<4;r++) len4[r] = lensh[quad*4 + r];

    for(int lb=0;lb<64;lb+=2){
        lstm_step<STOREH>(lb,   hbuf[0], hbuf[1], pxg, hsp, bfh, x0, x1, c4, lg4, len4, wcv, lc, quad, cw);
        lstm_step<STOREH>(lb+1, hbuf[1], hbuf[0], pxg, hsp, bfh, x1, x0, c4, lg4, len4, wcv, lc, quad, cw);
    }
    #pragma unroll
    for(int r=0;r<4;r++) lgsh[quad*4+r][cw] = lg4[r];
    __syncthreads();
    {
        int row = t >> 5, l32 = t & 31;
        float s = lgsh[row][l32] + lgsh[row][l32+32] + lgsh[row][l32+64] + lgsh[row][l32+96];
        s += __shfl_down(s, 16, 32);
        s += __shfl_down(s, 8, 32);
        s += __shfl_down(s, 4, 32);
        s += __shfl_down(s, 2, 32);
        s += __shfl_down(s, 1, 32);
        if(l32 == 0) logits_out[b0 + row] = s + bcls[0];
    }
}

// ---------------------------------------------------------------- fused: hp GEMM + diff_loss + reverse diffusion -> v_syn
__global__ __launch_bounds__(256,2) void k_drg(const float* __restrict__ v, const u16* __restrict__ h,
        const float* __restrict__ eps, const int* __restrict__ tdiff, const float* __restrict__ vmask,
        const float* __restrict__ z0, const float* __restrict__ noise, const float* __restrict__ temb,
        const float* __restrict__ Wf, const float* __restrict__ bfu,
        const u16* __restrict__ We1p, const float* __restrict__ be1,
        const u16* __restrict__ We2p, const float* __restrict__ be2,
        const u16* __restrict__ Wprojp,
        float* __restrict__ partial, float* __restrict__ vsyn){
    __shared__ __align__(16) float zbuf[16*ZS];
    __shared__ float hpbuf[16*ZS];
    __shared__ __align__(16) u16 xbuf[16*XS];
    __shared__ __align__(16) u16 y1buf[16*YS];
    __shared__ __align__(16) u16 hb16[16*HS2];
    __shared__ float wfsh[512];
    __shared__ float ssh[16][2], hpd[16][2];
    __shared__ float mrow[16]; __shared__ int trow[16];
    __shared__ float sbeta[10], sabar[10];
    __shared__ float rb[4];
    int row0 = blockIdx.x * 16; int t = threadIdx.x;
    int wave = t >> 6, lane = t & 63, quad = lane >> 4, lc = lane & 15;

    if(t==0){
        float p = 1.f;
        for(int k=0;k<10;k++){ float b = 1e-4f + (0.02f - 1e-4f)*k/9.f; sbeta[k] = b; p *= (1.f - b); sabar[k] = p; }
    }
    if(t < 16){
        int row = row0 + t; float m = vmask[row];
        mrow[t] = m; trow[t] = (m > 0.f) ? tdiff[row >> 6] : 1;
    }
    for(int i=t;i<512;i+=256) wfsh[i] = Wf[i];
    __syncthreads();
    // z_t staging + h_prev staging (bf16 rows row0-1..row0+14; l==0 row -> zeros)
    #pragma unroll
    for(int i=0;i<8;i++){
        int flat = i*256 + t; int r = flat >> 7; int e = flat & 127; int row = row0 + r;
        float ab = sabar[trow[r]-1];
        zbuf[r*ZS + e] = (sqrtf(ab)*v[(size_t)row*E_ + e] + sqrtf(1.f - ab)*eps[(size_t)row*E_ + e]) * mrow[r];
    }
    {
        int r = t >> 4, e0 = (t & 15) * 8;
        bf16x8 hv;
        if(((row0 & 63) == 0) && r == 0){
            hv = (bf16x8){0,0,0,0,0,0,0,0};
        } else {
            hv = *(const bf16x8*)(h + (size_t)(row0 - 1 + r)*E_ + e0);
        }
        *(bf16x8*)&hb16[r*HS2 + e0] = hv;
    }
    bf16x8 wf1[2][8], wf2[2][4], pf[2][4];
    float be1v[2], be2v[2];
    #pragma unroll
    for(int nt=0;nt<2;nt++){
        int n = wave*32 + nt*16 + lc;
        be1v[nt] = be1[n]; be2v[nt] = be2[n];
        #pragma unroll
        for(int kt=0;kt<8;kt++) wf1[nt][kt] = *(const bf16x8*)(We1p + (((wave*2+nt)*8+kt)<<9) + lane*8);
        #pragma unroll
        for(int kt=0;kt<4;kt++){
            wf2[nt][kt] = *(const bf16x8*)(We2p + (((wave*2+nt)*4+kt)<<9) + lane*8);
            pf[nt][kt]  = *(const bf16x8*)(Wprojp + (((wave*2+nt)*4+kt)<<9) + lane*8);
        }
    }
    __syncthreads();
    // hp = h_prev @ Wproj^T via MFMA (one-time)
    {
        f32x4 ap[2];
        ap[0] = (f32x4){0.f,0.f,0.f,0.f}; ap[1] = (f32x4){0.f,0.f,0.f,0.f};
        #pragma unroll
        for(int kt=0;kt<4;kt++){
            bf16x8 af = *(const bf16x8*)&hb16[lc*HS2 + kt*32 + quad*8];
            ap[0] = __builtin_amdgcn_mfma_f32_16x16x32_bf16(af, pf[0][kt], ap[0], 0,0,0);
            ap[1] = __builtin_amdgcn_mfma_f32_16x16x32_bf16(af, pf[1][kt], ap[1], 0,0,0);
        }
        #pragma unroll
        for(int nt=0;nt<2;nt++)
            #pragma unroll
            for(int rr=0;rr<4;rr++)
                hpbuf[(quad*4+rr)*ZS + wave*32 + nt*16 + lc] = ap[nt][rr];
    }
    __syncthreads();
    // hp·Wf[:,128:256]+bfu (reused by both diff and all 10 reverse steps)
    {
        int row = t >> 4, k = (t >> 3) & 1, sub = t & 7;
        float p = 0.f;
        #pragma unroll
        for(int i=0;i<16;i++)
            p += hpbuf[row*ZS + sub*16 + i] * wfsh[k*256 + 128 + sub*16 + i];
        p += __shfl_down(p,4); p += __shfl_down(p,2); p += __shfl_down(p,1);
        if(sub == 0) hpd[row][k] = p + bfu[k];
    }
    __syncthreads();

    // ---------- 11 fuse_eps evaluations: s=0 -> diff loss on z_t; s=1..10 -> reverse steps
    for(int s=0;s<11;s++){
        int kk = 11 - s;                // reverse step index for s>=1
        // prefetch this iteration's global inputs early (hidden under dot+MFMA phases)
        float nzv[8], epv[8], z0v[8];
        if(s >= 1){
            #pragma unroll
            for(int nt=0;nt<2;nt++)
                #pragma unroll
                for(int r=0;r<4;r++)
                    nzv[nt*4+r] = noise[((size_t)(s-1)*NROW + row0 + quad*4 + r)*E_ + wave*32 + nt*16 + lc];
        } else {
            #pragma unroll
            for(int nt=0;nt<2;nt++)
                #pragma unroll
                for(int r=0;r<4;r++)
                    epv[nt*4+r] = eps[(size_t)(row0 + quad*4 + r)*E_ + wave*32 + nt*16 + lc];
            #pragma unroll
            for(int i=0;i<8;i++){
                int flat = i*256 + t;
                z0v[i] = z0[(size_t)(row0 + (flat >> 7))*E_ + (flat & 127)];
            }
        }
        {
            int row = t >> 4, k = (t >> 3) & 1, sub = t & 7;
            float q = 0.f;
            #pragma unroll
            for(int i=0;i<16;i++)
                q += zbuf[row*ZS + sub*16 + i] * wfsh[k*256 + sub*16 + i];
            q += __shfl_down(q,4); q += __shfl_down(q,2); q += __shfl_down(q,1);
            if(sub == 0) ssh[row][k] = q + hpd[row][k];
        }
        __syncthreads();
        {
            int row = t >> 4, c0 = (t & 15) * 16;
            float s0 = ssh[row][0], s1 = ssh[row][1];
            float a0 = 1.f/(1.f + __expf(s1 - s0)), a1 = 1.f - a0;
            int tt = (s == 0) ? trow[row] : ((mrow[row] > 0.f) ? kk : 1);
            #pragma unroll
            for(int i=0;i<16;i++){
                int c = c0 + i;
                float val = (c < 128) ? (a0*zbuf[row*ZS + c] + a1*hpbuf[row*ZS + c])
                                      : temb[tt*E_ + (c - 128)];
                xbuf[row*XS + c] = f2bf(val);
            }
        }
        __syncthreads();
        f32x4 acc1[2];
        acc1[0] = (f32x4){0.f,0.f,0.f,0.f}; acc1[1] = (f32x4){0.f,0.f,0.f,0.f};
        #pragma unroll
        for(int kt=0;kt<8;kt++){
            bf16x8 af = *(const bf16x8*)&xbuf[lc*XS + kt*32 + quad*8];
            acc1[0] = __builtin_amdgcn_mfma_f32_16x16x32_bf16(af, wf1[0][kt], acc1[0], 0,0,0);
            acc1[1] = __builtin_amdgcn_mfma_f32_16x16x32_bf16(af, wf1[1][kt], acc1[1], 0,0,0);
        }
        #pragma unroll
        for(int nt=0;nt<2;nt++){
            #pragma unroll
            for(int r=0;r<4;r++)
                y1buf[(quad*4+r)*YS + wave*32 + nt*16 + lc] = f2bf(fmaxf(acc1[nt][r] + be1v[nt], 0.f));
        }
        __syncthreads();
        f32x4 acc2[2];
        acc2[0] = (f32x4){0.f,0.f,0.f,0.f}; acc2[1] = (f32x4){0.f,0.f,0.f,0.f};
        #pragma unroll
        for(int kt=0;kt<4;kt++){
            bf16x8 af = *(const bf16x8*)&y1buf[lc*YS + kt*32 + quad*8];
            acc2[0] = __builtin_amdgcn_mfma_f32_16x16x32_bf16(af, wf2[0][kt], acc2[0], 0,0,0);
            acc2[1] = __builtin_amdgcn_mfma_f32_16x16x32_bf16(af, wf2[1][kt], acc2[1], 0,0,0);
        }
        if(s == 0){
            // diffusion loss partial; then load z0 (prefetched) for the reverse chain
            float lp = 0.f;
            #pragma unroll
            for(int nt=0;nt<2;nt++){
                #pragma unroll
                for(int r=0;r<4;r++){
                    int m = quad*4 + r;
                    float d = (acc2[nt][r] + be2v[nt]) - epv[nt*4+r];
                    lp += d*d*mrow[m];
                }
            }
            #pragma unroll
            for(int off=32;off;off>>=1) lp += __shfl_down(lp, off);
            if(lane == 0) rb[wave] = lp;
            __syncthreads();
            if(t == 0) partial[blockIdx.x] = rb[0]+rb[1]+rb[2]+rb[3];
            #pragma unroll
            for(int i=0;i<8;i++){
                int flat = i*256 + t; int r = flat >> 7; int e = flat & 127;
                zbuf[r*ZS + e] = z0v[i];
            }
            __syncthreads();
        } else {
            float beta = sbeta[kk-1];
            float c1 = beta / sqrtf(1.f - sabar[kk-1]);
            float c2 = 1.f / sqrtf(1.f - beta);
            float sb = sqrtf(beta);
            #pragma unroll
            for(int nt=0;nt<2;nt++){
                int n = wave*32 + nt*16 + lc;
                #pragma unroll
                for(int r=0;r<4;r++){
                    int m = quad*4 + r;
                    float e = acc2[nt][r] + be2v[nt];
                    float z = zbuf[m*ZS + n];
                    float mean = (z - c1*e) * c2;
                    float nz = nzv[nt*4+r];
                    float znew = (kk > 1) ? (mean + sb*nz) : mean;
                    zbuf[m*ZS + n] = znew * mrow[m];
                }
            }
            __syncthreads();
        }
    }
    // ---------- write v_syn (final zbuf) as f32; lstm2's xg comes from k_gemm_xgp(vsyn)
    {
        int r = t >> 4, e0 = (t & 15) * 8;
        float4 a = *(const float4*)&zbuf[r*ZS + e0];
        float4 b2 = *(const float4*)&zbuf[r*ZS + e0 + 4];
        *(float4*)&vsyn[(size_t)(row0 + r)*E_ + e0] = a;
        *(float4*)&vsyn[(size_t)(row0 + r)*E_ + e0 + 4] = b2;
    }
}

// ---------------------------------------------------------------- loss finalize (sums 512 partials + mask)
__global__ void k_finalize(const float* __restrict__ partial, const float* __restrict__ vmask, float* __restrict__ out){
    __shared__ float rb[4], rl[4];
    int t = threadIdx.x;
    float s = 0.f;
    for(int i=t;i<NROW;i+=256) s += vmask[i];
    float ls = 0.f;
    for(int i=t;i<512;i+=256) ls += partial[i];
    #pragma unroll
    for(int off=32;off;off>>=1){ s += __shfl_down(s, off); ls += __shfl_down(ls, off); }
    if((t & 63) == 0){ rb[t >> 6] = s; rl[t >> 6] = ls; }
    __syncthreads();
    if(t == 0){
        float denom = rb[0]+rb[1]+rb[2]+rb[3];
        if(denom < 1.f) denom = 1.f;
        out[256] = (rl[0]+rl[1]+rl[2]+rl[3]) / denom;
    }
}

extern "C" void kernel_launch(void* const* d_in, const int* in_sizes, int n_in,
                              void* d_out, int out_size, void* d_ws, size_t ws_size,
                              hipStream_t stream){
    const float* px    = (const float*)d_in[0];
    const float* vmask = (const float*)d_in[1];
    const int*   bins  = (const int*)d_in[2];
    const int*   tdiff = (const int*)d_in[3];
    const float* eps   = (const float*)d_in[4];
    const float* z0    = (const float*)d_in[5];
    const float* noise = (const float*)d_in[6];
    const float* Wv    = (const float*)d_in[7];
    const float* bemb  = (const float*)d_in[8];
    const float* Wih   = (const float*)d_in[9];
    const float* Whh   = (const float*)d_in[10];
    const float* bih   = (const float*)d_in[11];
    const float* bhh   = (const float*)d_in[12];
    const float* Wcls  = (const float*)d_in[13];
    const float* bcls  = (const float*)d_in[14];
    const float* Wproj = (const float*)d_in[15];
    const float* temb  = (const float*)d_in[16];
    const float* Wf    = (const float*)d_in[17];
    const float* bfu   = (const float*)d_in[18];
    const float* We1   = (const float*)d_in[19];
    const float* be1   = (const float*)d_in[20];
    const float* We2   = (const float*)d_in[21];
    const float* be2   = (const float*)d_in[22];
    float* out = (float*)d_out;

    float* ws = (float*)d_ws;
    float* xgp     = ws;                        // 4,194,304 fl (16 MB), reused pass1/pass2
    float* WT      = ws + 4194304;              // 1,048,576 fl; dead after k_visit_embed
    u16*  Whh_p    = (u16*)(ws + 4194304);      // overlays WT region (written after visit)
    u16*  Wih_p    = (u16*)(ws + 4227072);
    u16*  We1_p    = (u16*)(ws + 4259840);
    u16*  We2_p    = (u16*)(ws + 4276224);
    u16*  Wproj_p  = (u16*)(ws + 4284416);
    u16*  h_store  = (u16*)(ws + 4292608);      // 1,048,576 u16 = 524,288 fl
    float* v       = ws + 5242880;              // 1,048,576
    float* vsyn    = ws + 6291456;              // 1,048,576
    float* partial = ws + 7340032;              // 512

    hipLaunchKernelGGL(k_transpose_wv, dim3(V_/16), dim3(256), 0, stream, Wv, WT);
    hipLaunchKernelGGL(k_visit_embed, dim3(NROW), dim3(256), 0, stream, px, vmask, bins, bemb, WT, v);
    hipLaunchKernelGGL(k_pack, dim3(96), dim3(256), 0, stream, Whh, Wih, We1, We2, Wproj,
                       Whh_p, Wih_p, We1_p, We2_p, Wproj_p);
    hipLaunchKernelGGL(k_gemm_xgp, dim3(512), dim3(256), 0, stream, v, Wih_p, bih, bhh, xgp);
    hipLaunchKernelGGL((k_lstm<true>), dim3(B_/16), dim3(512), 0, stream,
                       xgp, Whh_p, Wcls, bcls, vmask, h_store, out);
    hipLaunchKernelGGL(k_drg, dim3(NROW/16), dim3(256), 0, stream,
                       v, h_store, eps, tdiff, vmask, z0, noise, temb, Wf, bfu,
                       We1_p, be1, We2_p, be2, Wproj_p, partial, vsyn);
    hipLaunchKernelGGL(k_gemm_xgp, dim3(512), dim3(256), 0, stream, vsyn, Wih_p, bih, bhh, xgp);
    hipLaunchKernelGGL((k_lstm<false>), dim3(B_/16), dim3(512), 0, stream,
                       xgp, Whh_p, Wcls, bcls, vmask, (u16*)nullptr, out + 128);
    hipLaunchKernelGGL(k_finalize, dim3(1), dim3(256), 0, stream, partial, vmask, out);
}

// Round 5
// 725.432 us; speedup vs baseline: 1.1360x; 1.0233x over previous
//
#include <hip/hip_runtime.h>

#define B_ 128
#define L_ 64
#define V_ 8192
#define E_ 128
#define H_ 128
#define NROW (B_*L_)
#define HSTRIDE 136
#define AS 136
#define XS 264
#define YS 136
#define ZS 132
#define HS2 136

typedef unsigned short u16;
typedef __attribute__((ext_vector_type(8))) short bf16x8;
typedef __attribute__((ext_vector_type(4))) float f32x4;

__device__ __forceinline__ float sigm(float x){ return 1.f/(1.f + __expf(-x)); }
__device__ __forceinline__ float ftanh(float x){ float e = __expf(2.f*x); return 1.f - 2.f/(e + 1.f); }
__device__ __forceinline__ u16 f2bf(float f){
    union { unsigned int i; float f; } x; x.f = f;
    unsigned int r = x.i + 0x7fff + ((x.i >> 16) & 1);
    return (u16)(r >> 16);
}
// raw barrier: LDS-only sync, no vmcnt drain (global loads/stores stay in flight)
#define LBAR() asm volatile("s_waitcnt lgkmcnt(0)\ns_barrier" ::: "memory")

__device__ __forceinline__ bf16x8 pack8(const float* p){
    const float4* q = (const float4*)p;
    float4 a = q[0], b = q[1];
    bf16x8 f;
    f[0]=(short)f2bf(a.x); f[1]=(short)f2bf(a.y); f[2]=(short)f2bf(a.z); f[3]=(short)f2bf(a.w);
    f[4]=(short)f2bf(b.x); f[5]=(short)f2bf(b.y); f[6]=(short)f2bf(b.z); f[7]=(short)f2bf(b.w);
    return f;
}

// ---------------------------------------------------------------- prep: transpose W_visit (blocks 0..511) + pack MFMA weights (blocks 512..607)
// pack layout: groups of 512 u16; group=((w*NT+nt)*KT+kt); elem lane*8+j; src n = w*WS + nt*TS + lc, k = kt*32+quad*8+j
__global__ __launch_bounds__(256) void k_prep(const float* __restrict__ Wv, float* __restrict__ WT,
                                              const float* __restrict__ Whh, const float* __restrict__ Wih,
                                              const float* __restrict__ We1, const float* __restrict__ We2,
                                              const float* __restrict__ Wproj,
                                              u16* __restrict__ dWhh, u16* __restrict__ dWih,
                                              u16* __restrict__ dWe1, u16* __restrict__ dWe2,
                                              u16* __restrict__ dWproj){
    __shared__ float tile[16][129];
    int t = threadIdx.x;
    if(blockIdx.x < 512){
        int v0 = blockIdx.x * 16;
        #pragma unroll
        for(int i=0;i<8;i++){
            int idx = i*256 + t; int e = idx >> 4; int vv = idx & 15;
            tile[vv][e] = Wv[(size_t)e*V_ + v0 + vv];
        }
        __syncthreads();
        #pragma unroll
        for(int i=0;i<8;i++){
            int idx = i*256 + t; int vv = idx >> 7; int e = idx & 127;
            WT[(size_t)(v0+vv)*E_ + e] = tile[vv][e];
        }
        return;
    }
    int bid = blockIdx.x - 512;
    const float* src; u16* dst; int WS,TS,NT,KT,K; int base;
    if(bid<32){ src=Whh; dst=dWhh; WS=16; TS=128; NT=4; KT=4; K=128; base=bid; }
    else if(bid<64){ src=Wih; dst=dWih; WS=128; TS=16; NT=8; KT=4; K=128; base=bid-32; }
    else if(bid<80){ src=We1; dst=dWe1; WS=32; TS=16; NT=2; KT=8; K=256; base=bid-64; }
    else if(bid<88){ src=We2; dst=dWe2; WS=32; TS=16; NT=2; KT=4; K=128; base=bid-80; }
    else { src=Wproj; dst=dWproj; WS=32; TS=16; NT=2; KT=4; K=128; base=bid-88; }
    for(int i=0;i<8;i++){
        int o = base*2048 + i*256 + t;
        int g = o >> 9; int lane = (o >> 3) & 63; int j = o & 7;
        int kt = g % KT; int r2 = g / KT; int nt = r2 % NT; int w = r2 / NT;
        int lc = lane & 15; int quad = lane >> 4;
        int n = w*WS + nt*TS + lc; int k = kt*32 + quad*8 + j;
        dst[o] = f2bf(src[(size_t)n*K + k]);
    }
}

// ---------------------------------------------------------------- v = (x @ Wv^T + bin_embed[delta]) * m
__global__ __launch_bounds__(256) void k_visit_embed(const float* __restrict__ px, const float* __restrict__ vmask,
                                                     const int* __restrict__ bins, const float* __restrict__ bemb,
                                                     const float* __restrict__ WT, float* __restrict__ v){
    __shared__ int idxs[512];
    __shared__ int cnt;
    __shared__ int dsh;
    __shared__ float msh;
    __shared__ float4 red[8][32];
    int row = blockIdx.x; int l = row & 63;
    int t = threadIdx.x;
    if(t==0){
        cnt = 0;
        float m = vmask[row];
        int d = 0;
        if(l > 0){ d = bins[row] - bins[row-1]; d = d < 0 ? 0 : (d > 513 ? 513 : d); }
        if(!(m > 0.f)) d = 0;
        dsh = d; msh = m;
    }
    __syncthreads();
    // issue all 8 uint4 loads upfront (128 B/thread in flight) before the
    // dependent test/compact loop -> full memory-level parallelism on the
    // 268 MB px stream instead of one load per branchy iteration.
    const uint4* xr4 = (const uint4*)(px + (size_t)row * V_);
    uint4 u8[8];
    #pragma unroll
    for(int i=0;i<8;i++) u8[i] = xr4[t + i*256];
    #pragma unroll
    for(int i=0;i<8;i++){
        unsigned int w[4] = {u8[i].x,u8[i].y,u8[i].z,u8[i].w};
        #pragma unroll
        for(int j=0;j<4;j++){
            if(w[j]){ int p = atomicAdd(&cnt,1); if(p<512) idxs[p] = (t + i*256)*4 + j; }
        }
    }
    __syncthreads();
    int n = cnt; if(n > 512) n = 512;
    int eq = t & 31, jg = t >> 5;
    float4 a4 = {0.f,0.f,0.f,0.f};
    for(int j=jg;j<n;j+=8){
        const float4* wr = (const float4*)(WT + (size_t)idxs[j]*E_);
        float4 wv = wr[eq];
        a4.x += wv.x; a4.y += wv.y; a4.z += wv.z; a4.w += wv.w;
    }
    red[jg][eq] = a4;
    __syncthreads();
    if(t < 32){
        float4 s = red[0][t];
        #pragma unroll
        for(int g=1;g<8;g++){
            float4 r = red[g][t];
            s.x += r.x; s.y += r.y; s.z += r.z; s.w += r.w;
        }
        const float4* bp = (const float4*)(bemb + dsh*E_);
        float4 bv = bp[t];
        float m = msh;
        float4 o;
        o.x = (s.x + bv.x)*m; o.y = (s.y + bv.y)*m; o.z = (s.z + bv.z)*m; o.w = (s.w + bv.w)*m;
        ((float4*)(v + (size_t)row*E_))[t] = o;
    }
}

// ---------------------------------------------------------------- xg = A @ Wih^T + b, stored lstm-thread-major
// block = (bg, l0/2): 2 l-slabs per block (weight frags amortized). slab [sid][512 thr][16 floats]
__global__ __launch_bounds__(256,2) void k_gemm_xgp(const float* __restrict__ A, const u16* __restrict__ Wihp,
                                                    const float* __restrict__ bih, const float* __restrict__ bhh,
                                                    float* __restrict__ xgp){
    __shared__ __align__(16) u16 abuf[2][16*AS];
    int t = threadIdx.x, wave = t >> 6, lane = t & 63, quad = lane >> 4, lc = lane & 15;
    int bid = blockIdx.x; int bg = bid >> 5, l0 = (bid & 31)*2;
    #pragma unroll
    for(int i=0;i<16;i++){
        int flat = i*256 + t; int s = flat >> 11; int r = (flat >> 7) & 15; int e = flat & 127;
        abuf[s][r*AS + e] = f2bf(A[((size_t)(bg*16+r)*64 + l0 + s)*E_ + e]);
    }
    bf16x8 wg[8][4]; float bb[8];
    #pragma unroll
    for(int nt=0;nt<8;nt++){
        int n = wave*128 + nt*16 + lc;
        bb[nt] = bih[n] + bhh[n];
        #pragma unroll
        for(int kt=0;kt<4;kt++)
            wg[nt][kt] = *(const bf16x8*)(Wihp + (((wave*8+nt)*4+kt)<<9) + lane*8);
    }
    __syncthreads();
    #pragma unroll
    for(int s=0;s<2;s++){
        f32x4 ac[8];
        #pragma unroll
        for(int nt=0;nt<8;nt++) ac[nt] = (f32x4){0.f,0.f,0.f,0.f};
        #pragma unroll
        for(int kt=0;kt<4;kt++){
            bf16x8 af = *(const bf16x8*)&abuf[s][lc*AS + kt*32 + quad*8];
            #pragma unroll
            for(int nt=0;nt<8;nt++)
                ac[nt] = __builtin_amdgcn_mfma_f32_16x16x32_bf16(af, wg[nt][kt], ac[nt], 0,0,0);
        }
        float* dst = xgp + (size_t)(bg*64 + l0 + s)*8192;
        #pragma unroll
        for(int nt=0;nt<8;nt++){
            float4 o;
            o.x = ac[nt][0] + bb[nt]; o.y = ac[nt][1] + bb[nt];
            o.z = ac[nt][2] + bb[nt]; o.w = ac[nt][3] + bb[nt];
            *(float4*)(dst + nt*1024 + quad*256 + lc*16 + wave*4) = o;
        }
    }
}

// ---------------------------------------------------------------- LSTM: recurrence only (xg precomputed) + logits
template<bool STOREH>
__device__ __forceinline__ void lstm_step(int l,
        const u16* __restrict__ bufr, u16* __restrict__ bufw,
        const f32x4*& pxg, u16* hsp,
        const bf16x8 (&bfh)[4][4],
        f32x4 (&xc)[4], f32x4 (&xn)[4], float (&c4)[4], float (&lg4)[4],
        const int (&len4)[4], float wcv, int lc, int quad, int cw){
    // prefetch next step's xg (4 contiguous float4s per thread)
    if(l+1 < 64){
        #pragma unroll
        for(int g=0;g<4;g++) xn[g] = pxg[g];
        pxg += 2048;
    }
    bf16x8 afh[4];
    #pragma unroll
    for(int kt=0;kt<4;kt++)
        afh[kt] = *(const bf16x8*)&bufr[lc*HSTRIDE + kt*32 + quad*8];
    f32x4 acc[4];
    #pragma unroll
    for(int g=0;g<4;g++) acc[g] = (f32x4){0.f,0.f,0.f,0.f};
    #pragma unroll
    for(int kt=0;kt<4;kt++){
        #pragma unroll
        for(int g=0;g<4;g++)
            acc[g] = __builtin_amdgcn_mfma_f32_16x16x32_bf16(afh[kt], bfh[g][kt], acc[g], 0,0,0);
    }
    #pragma unroll
    for(int r=0;r<4;r++){
        float gi = acc[0][r] + xc[0][r];
        float gf = acc[1][r] + xc[1][r];
        float gg = acc[2][r] + xc[2][r];
        float go = acc[3][r] + xc[3][r];
        float c  = sigm(gf)*c4[r] + sigm(gi)*ftanh(gg);
        float h  = sigm(go)*ftanh(c);
        c4[r] = c;
        u16 hb = f2bf(h);
        bufw[(quad*4+r)*HSTRIDE + cw] = hb;
        if constexpr (STOREH) hsp[(size_t)r*8192 + (size_t)l*128] = hb;
        if(l == len4[r]-1) lg4[r] += h * wcv;
    }
    LBAR();
}

// grid = 8 blocks on 256 CUs -> occupancy is irrelevant; waves_per_eu(2,2) tells the
// scheduler its pressure target is 2 waves/SIMD (256 VGPR budget) so the ~150-VGPR
// loop-resident set (bfh 64 + xg dbuf 32 + acc/frags) stays resident. Weight frags
// are plain loads from pre-packed bf16 (k_prep) -> even if rematerialized, it's one
// L2-hit dwordx4, not a 48-VALU f32->bf16 repack.
template<bool STOREH>
__global__ __attribute__((amdgpu_waves_per_eu(2,2))) __launch_bounds__(512)
void k_lstm(const float* __restrict__ xgp, const u16* __restrict__ Whhp,
            const float* __restrict__ Wcls, const float* __restrict__ bcls,
            const float* __restrict__ vmask, u16* __restrict__ h_store,
            float* __restrict__ logits_out){
    __shared__ __align__(16) u16 hbuf[2][16*HSTRIDE];
    __shared__ float vmsh[16*64];
    __shared__ int lensh[16];
    __shared__ float lgsh[16][132];
    int t = threadIdx.x;
    int wave = t >> 6, lane = t & 63;
    int quad = lane >> 4, lc = lane & 15;
    int cw = wave*16 + lc;
    int bg = blockIdx.x; int b0 = bg * 16;

    for(int i=t;i<16*HSTRIDE;i+=512) hbuf[0][i] = 0;
    for(int i=t;i<1024;i+=512) vmsh[i] = vmask[b0*64 + i];
    __syncthreads();
    if(t < 16){
        int s = 0;
        #pragma unroll
        for(int i=0;i<64;i++) s += (vmsh[t*64 + i] > 0.f) ? 1 : 0;
        lensh[t] = s < 1 ? 1 : s;
    }

    bf16x8 bfh[4][4];
    #pragma unroll
    for(int g=0;g<4;g++)
        #pragma unroll
        for(int kt=0;kt<4;kt++)
            bfh[g][kt] = *(const bf16x8*)(Whhp + (((wave*4+g)*4+kt)<<9) + lane*8);
    float wcv = Wcls[cw];
    float c4[4] = {0.f,0.f,0.f,0.f};
    float lg4[4] = {0.f,0.f,0.f,0.f};
    u16* hsp = STOREH ? (h_store + ((size_t)(b0 + quad*4)*64)*128 + cw) : (u16*)nullptr;

    const f32x4* pxg = (const f32x4*)(xgp + (size_t)bg*64*8192) + t*4;
    f32x4 x0[4], x1[4];
    #pragma unroll
    for(int g=0;g<4;g++) x0[g] = pxg[g];
    pxg += 2048;
    __syncthreads();
    int len4[4];
    #pragma unroll
    for(int r=0;r<4;r++) len4[r] = lensh[quad*4 + r];

    for(int lb=0;lb<64;lb+=2){
        lstm_step<STOREH>(lb,   hbuf[0], hbuf[1], pxg, hsp, bfh, x0, x1, c4, lg4, len4, wcv, lc, quad, cw);
        lstm_step<STOREH>(lb+1, hbuf[1], hbuf[0], pxg, hsp, bfh, x1, x0, c4, lg4, len4, wcv, lc, quad, cw);
    }
    #pragma unroll
    for(int r=0;r<4;r++) lgsh[quad*4+r][cw] = lg4[r];
    __syncthreads();
    {
        int row = t >> 5, l32 = t & 31;
        float s = lgsh[row][l32] + lgsh[row][l32+32] + lgsh[row][l32+64] + lgsh[row][l32+96];
        s += __shfl_down(s, 16, 32);
        s += __shfl_down(s, 8, 32);
        s += __shfl_down(s, 4, 32);
        s += __shfl_down(s, 2, 32);
        s += __shfl_down(s, 1, 32);
        if(l32 == 0) logits_out[b0 + row] = s + bcls[0];
    }
}

// ---------------------------------------------------------------- fused: hp GEMM + diff_loss + reverse diffusion -> v_syn
__global__ __launch_bounds__(256,2) void k_drg(const float* __restrict__ v, const u16* __restrict__ h,
        const float* __restrict__ eps, const int* __restrict__ tdiff, const float* __restrict__ vmask,
        const float* __restrict__ z0, const float* __restrict__ noise, const float* __restrict__ temb,
        const float* __restrict__ Wf, const float* __restrict__ bfu,
        const u16* __restrict__ We1p, const float* __restrict__ be1,
        const u16* __restrict__ We2p, const float* __restrict__ be2,
        const u16* __restrict__ Wprojp,
        float* __restrict__ partial, float* __restrict__ vsyn){
    __shared__ __align__(16) float zbuf[16*ZS];
    __shared__ float hpbuf[16*ZS];
    __shared__ __align__(16) u16 xbuf[16*XS];
    __shared__ __align__(16) u16 y1buf[16*YS];
    __shared__ __align__(16) u16 hb16[16*HS2];
    __shared__ float wfsh[512];
    __shared__ float ssh[16][2], hpd[16][2];
    __shared__ float mrow[16]; __shared__ int trow[16];
    __shared__ float sbeta[10], sabar[10];
    __shared__ float rb[4];
    int row0 = blockIdx.x * 16; int t = threadIdx.x;
    int wave = t >> 6, lane = t & 63, quad = lane >> 4, lc = lane & 15;

    if(t==0){
        float p = 1.f;
        for(int k=0;k<10;k++){ float b = 1e-4f + (0.02f - 1e-4f)*k/9.f; sbeta[k] = b; p *= (1.f - b); sabar[k] = p; }
    }
    if(t < 16){
        int row = row0 + t; float m = vmask[row];
        mrow[t] = m; trow[t] = (m > 0.f) ? tdiff[row >> 6] : 1;
    }
    for(int i=t;i<512;i+=256) wfsh[i] = Wf[i];
    __syncthreads();
    // z_t staging + h_prev staging (bf16 rows row0-1..row0+14; l==0 row -> zeros)
    #pragma unroll
    for(int i=0;i<8;i++){
        int flat = i*256 + t; int r = flat >> 7; int e = flat & 127; int row = row0 + r;
        float ab = sabar[trow[r]-1];
        zbuf[r*ZS + e] = (sqrtf(ab)*v[(size_t)row*E_ + e] + sqrtf(1.f - ab)*eps[(size_t)row*E_ + e]) * mrow[r];
    }
    {
        int r = t >> 4, e0 = (t & 15) * 8;
        bf16x8 hv;
        if(((row0 & 63) == 0) && r == 0){
            hv = (bf16x8){0,0,0,0,0,0,0,0};
        } else {
            hv = *(const bf16x8*)(h + (size_t)(row0 - 1 + r)*E_ + e0);
        }
        *(bf16x8*)&hb16[r*HS2 + e0] = hv;
    }
    bf16x8 wf1[2][8], wf2[2][4], pf[2][4];
    float be1v[2], be2v[2];
    #pragma unroll
    for(int nt=0;nt<2;nt++){
        int n = wave*32 + nt*16 + lc;
        be1v[nt] = be1[n]; be2v[nt] = be2[n];
        #pragma unroll
        for(int kt=0;kt<8;kt++) wf1[nt][kt] = *(const bf16x8*)(We1p + (((wave*2+nt)*8+kt)<<9) + lane*8);
        #pragma unroll
        for(int kt=0;kt<4;kt++){
            wf2[nt][kt] = *(const bf16x8*)(We2p + (((wave*2+nt)*4+kt)<<9) + lane*8);
            pf[nt][kt]  = *(const bf16x8*)(Wprojp + (((wave*2+nt)*4+kt)<<9) + lane*8);
        }
    }
    __syncthreads();
    // hp = h_prev @ Wproj^T via MFMA (one-time)
    {
        f32x4 ap[2];
        ap[0] = (f32x4){0.f,0.f,0.f,0.f}; ap[1] = (f32x4){0.f,0.f,0.f,0.f};
        #pragma unroll
        for(int kt=0;kt<4;kt++){
            bf16x8 af = *(const bf16x8*)&hb16[lc*HS2 + kt*32 + quad*8];
            ap[0] = __builtin_amdgcn_mfma_f32_16x16x32_bf16(af, pf[0][kt], ap[0], 0,0,0);
            ap[1] = __builtin_amdgcn_mfma_f32_16x16x32_bf16(af, pf[1][kt], ap[1], 0,0,0);
        }
        #pragma unroll
        for(int nt=0;nt<2;nt++)
            #pragma unroll
            for(int rr=0;rr<4;rr++)
                hpbuf[(quad*4+rr)*ZS + wave*32 + nt*16 + lc] = ap[nt][rr];
    }
    __syncthreads();
    // hp·Wf[:,128:256]+bfu (reused by both diff and all 10 reverse steps)
    {
        int row = t >> 4, k = (t >> 3) & 1, sub = t & 7;
        float p = 0.f;
        #pragma unroll
        for(int i=0;i<16;i++)
            p += hpbuf[row*ZS + sub*16 + i] * wfsh[k*256 + 128 + sub*16 + i];
        p += __shfl_down(p,4); p += __shfl_down(p,2); p += __shfl_down(p,1);
        if(sub == 0) hpd[row][k] = p + bfu[k];
    }
    __syncthreads();

    // ---------- 11 fuse_eps evaluations: s=0 -> diff loss on z_t; s=1..10 -> reverse steps
    for(int s=0;s<11;s++){
        int kk = 11 - s;                // reverse step index for s>=1
        // prefetch this iteration's global inputs early (hidden under dot+MFMA phases)
        float nzv[8], epv[8], z0v[8];
        if(s >= 1){
            #pragma unroll
            for(int nt=0;nt<2;nt++)
                #pragma unroll
                for(int r=0;r<4;r++)
                    nzv[nt*4+r] = noise[((size_t)(s-1)*NROW + row0 + quad*4 + r)*E_ + wave*32 + nt*16 + lc];
        } else {
            #pragma unroll
            for(int nt=0;nt<2;nt++)
                #pragma unroll
                for(int r=0;r<4;r++)
                    epv[nt*4+r] = eps[(size_t)(row0 + quad*4 + r)*E_ + wave*32 + nt*16 + lc];
            #pragma unroll
            for(int i=0;i<8;i++){
                int flat = i*256 + t;
                z0v[i] = z0[(size_t)(row0 + (flat >> 7))*E_ + (flat & 127)];
            }
        }
        {
            int row = t >> 4, k = (t >> 3) & 1, sub = t & 7;
            float q = 0.f;
            #pragma unroll
            for(int i=0;i<16;i++)
                q += zbuf[row*ZS + sub*16 + i] * wfsh[k*256 + sub*16 + i];
            q += __shfl_down(q,4); q += __shfl_down(q,2); q += __shfl_down(q,1);
            if(sub == 0) ssh[row][k] = q + hpd[row][k];
        }
        __syncthreads();
        {
            int row = t >> 4, c0 = (t & 15) * 16;
            float s0 = ssh[row][0], s1 = ssh[row][1];
            float a0 = 1.f/(1.f + __expf(s1 - s0)), a1 = 1.f - a0;
            int tt = (s == 0) ? trow[row] : ((mrow[row] > 0.f) ? kk : 1);
            #pragma unroll
            for(int i=0;i<16;i++){
                int c = c0 + i;
                float val = (c < 128) ? (a0*zbuf[row*ZS + c] + a1*hpbuf[row*ZS + c])
                                      : temb[tt*E_ + (c - 128)];
                xbuf[row*XS + c] = f2bf(val);
            }
        }
        __syncthreads();
        f32x4 acc1[2];
        acc1[0] = (f32x4){0.f,0.f,0.f,0.f}; acc1[1] = (f32x4){0.f,0.f,0.f,0.f};
        #pragma unroll
        for(int kt=0;kt<8;kt++){
            bf16x8 af = *(const bf16x8*)&xbuf[lc*XS + kt*32 + quad*8];
            acc1[0] = __builtin_amdgcn_mfma_f32_16x16x32_bf16(af, wf1[0][kt], acc1[0], 0,0,0);
            acc1[1] = __builtin_amdgcn_mfma_f32_16x16x32_bf16(af, wf1[1][kt], acc1[1], 0,0,0);
        }
        #pragma unroll
        for(int nt=0;nt<2;nt++){
            #pragma unroll
            for(int r=0;r<4;r++)
                y1buf[(quad*4+r)*YS + wave*32 + nt*16 + lc] = f2bf(fmaxf(acc1[nt][r] + be1v[nt], 0.f));
        }
        __syncthreads();
        f32x4 acc2[2];
        acc2[0] = (f32x4){0.f,0.f,0.f,0.f}; acc2[1] = (f32x4){0.f,0.f,0.f,0.f};
        #pragma unroll
        for(int kt=0;kt<4;kt++){
            bf16x8 af = *(const bf16x8*)&y1buf[lc*YS + kt*32 + quad*8];
            acc2[0] = __builtin_amdgcn_mfma_f32_16x16x32_bf16(af, wf2[0][kt], acc2[0], 0,0,0);
            acc2[1] = __builtin_amdgcn_mfma_f32_16x16x32_bf16(af, wf2[1][kt], acc2[1], 0,0,0);
        }
        if(s == 0){
            // diffusion loss partial; then load z0 (prefetched) for the reverse chain
            float lp = 0.f;
            #pragma unroll
            for(int nt=0;nt<2;nt++){
                #pragma unroll
                for(int r=0;r<4;r++){
                    int m = quad*4 + r;
                    float d = (acc2[nt][r] + be2v[nt]) - epv[nt*4+r];
                    lp += d*d*mrow[m];
                }
            }
            #pragma unroll
            for(int off=32;off;off>>=1) lp += __shfl_down(lp, off);
            if(lane == 0) rb[wave] = lp;
            __syncthreads();
            if(t == 0) partial[blockIdx.x] = rb[0]+rb[1]+rb[2]+rb[3];
            #pragma unroll
            for(int i=0;i<8;i++){
                int flat = i*256 + t; int r = flat >> 7; int e = flat & 127;
                zbuf[r*ZS + e] = z0v[i];
            }
            __syncthreads();
        } else {
            float beta = sbeta[kk-1];
            float c1 = beta / sqrtf(1.f - sabar[kk-1]);
            float c2 = 1.f / sqrtf(1.f - beta);
            float sb = sqrtf(beta);
            #pragma unroll
            for(int nt=0;nt<2;nt++){
                int n = wave*32 + nt*16 + lc;
                #pragma unroll
                for(int r=0;r<4;r++){
                    int m = quad*4 + r;
                    float e = acc2[nt][r] + be2v[nt];
                    float z = zbuf[m*ZS + n];
                    float mean = (z - c1*e) * c2;
                    float nz = nzv[nt*4+r];
                    float znew = (kk > 1) ? (mean + sb*nz) : mean;
                    zbuf[m*ZS + n] = znew * mrow[m];
                }
            }
            __syncthreads();
        }
    }
    // ---------- write v_syn (final zbuf) as f32; lstm2's xg comes from k_gemm_xgp(vsyn)
    {
        int r = t >> 4, e0 = (t & 15) * 8;
        float4 a = *(const float4*)&zbuf[r*ZS + e0];
        float4 b2 = *(const float4*)&zbuf[r*ZS + e0 + 4];
        *(float4*)&vsyn[(size_t)(row0 + r)*E_ + e0] = a;
        *(float4*)&vsyn[(size_t)(row0 + r)*E_ + e0 + 4] = b2;
    }
}

// ---------------------------------------------------------------- loss finalize (sums 512 partials + mask)
__global__ void k_finalize(const float* __restrict__ partial, const float* __restrict__ vmask, float* __restrict__ out){
    __shared__ float rb[4], rl[4];
    int t = threadIdx.x;
    float s = 0.f;
    for(int i=t;i<NROW;i+=256) s += vmask[i];
    float ls = 0.f;
    for(int i=t;i<512;i+=256) ls += partial[i];
    #pragma unroll
    for(int off=32;off;off>>=1){ s += __shfl_down(s, off); ls += __shfl_down(ls, off); }
    if((t & 63) == 0){ rb[t >> 6] = s; rl[t >> 6] = ls; }
    __syncthreads();
    if(t == 0){
        float denom = rb[0]+rb[1]+rb[2]+rb[3];
        if(denom < 1.f) denom = 1.f;
        out[256] = (rl[0]+rl[1]+rl[2]+rl[3]) / denom;
    }
}

extern "C" void kernel_launch(void* const* d_in, const int* in_sizes, int n_in,
                              void* d_out, int out_size, void* d_ws, size_t ws_size,
                              hipStream_t stream){
    const float* px    = (const float*)d_in[0];
    const float* vmask = (const float*)d_in[1];
    const int*   bins  = (const int*)d_in[2];
    const int*   tdiff = (const int*)d_in[3];
    const float* eps   = (const float*)d_in[4];
    const float* z0    = (const float*)d_in[5];
    const float* noise = (const float*)d_in[6];
    const float* Wv    = (const float*)d_in[7];
    const float* bemb  = (const float*)d_in[8];
    const float* Wih   = (const float*)d_in[9];
    const float* Whh   = (const float*)d_in[10];
    const float* bih   = (const float*)d_in[11];
    const float* bhh   = (const float*)d_in[12];
    const float* Wcls  = (const float*)d_in[13];
    const float* bcls  = (const float*)d_in[14];
    const float* Wproj = (const float*)d_in[15];
    const float* temb  = (const float*)d_in[16];
    const float* Wf    = (const float*)d_in[17];
    const float* bfu   = (const float*)d_in[18];
    const float* We1   = (const float*)d_in[19];
    const float* be1   = (const float*)d_in[20];
    const float* We2   = (const float*)d_in[21];
    const float* be2   = (const float*)d_in[22];
    float* out = (float*)d_out;

    float* ws = (float*)d_ws;
    float* xgp     = ws;                        // 4,194,304 fl (16 MB), reused pass1/pass2
    float* WT      = ws + 4194304;              // 1,048,576 fl
    float* v       = ws + 5242880;              // 1,048,576
    float* vsyn    = ws + 6291456;              // 1,048,576
    float* partial = ws + 7340032;              // 512
    // packed bf16 weight fragments (own region; no longer aliases WT so k_prep
    // can transpose+pack in a single launch before anything else)
    u16*  Whh_p    = (u16*)(ws + 7340544);      // 65536 u16
    u16*  Wih_p    = Whh_p + 65536;             // 65536
    u16*  We1_p    = Whh_p + 131072;            // 32768
    u16*  We2_p    = Whh_p + 163840;            // 16384
    u16*  Wproj_p  = Whh_p + 180224;            // 16384 (end 196608 u16)
    u16*  h_store  = (u16*)(ws + 7438848);      // 1,048,576 u16 = 2 MB

    hipLaunchKernelGGL(k_prep, dim3(608), dim3(256), 0, stream, Wv, WT,
                       Whh, Wih, We1, We2, Wproj, Whh_p, Wih_p, We1_p, We2_p, Wproj_p);
    hipLaunchKernelGGL(k_visit_embed, dim3(NROW), dim3(256), 0, stream, px, vmask, bins, bemb, WT, v);
    hipLaunchKernelGGL(k_gemm_xgp, dim3(256), dim3(256), 0, stream, v, Wih_p, bih, bhh, xgp);
    hipLaunchKernelGGL((k_lstm<true>), dim3(B_/16), dim3(512), 0, stream,
                       xgp, Whh_p, Wcls, bcls, vmask, h_store, out);
    hipLaunchKernelGGL(k_drg, dim3(NROW/16), dim3(256), 0, stream,
                       v, h_store, eps, tdiff, vmask, z0, noise, temb, Wf, bfu,
                       We1_p, be1, We2_p, be2, Wproj_p, partial, vsyn);
    hipLaunchKernelGGL(k_gemm_xgp, dim3(256), dim3(256), 0, stream, vsyn, Wih_p, bih, bhh, xgp);
    hipLaunchKernelGGL((k_lstm<false>), dim3(B_/16), dim3(512), 0, stream,
                       xgp, Whh_p, Wcls, bcls, vmask, (u16*)nullptr, out + 128);
    hipLaunchKernelGGL(k_finalize, dim3(1), dim3(256), 0, stream, partial, vmask, out);
}